// Round 7
// baseline (118585.327 us; speedup 1.0000x reference)
//
#include <hip/hip_runtime.h>
#include <math.h>
#include <stdint.h>

#define TT 2048
#define BB 64
#define II 256
#define HH 512
#define EHD 128
#define NGATE 64
#define NWG 72
#define ARRV 68   // arrivals per barrier: 64 gate + 4 encoder (alternating group)

typedef __attribute__((ext_vector_type(8))) short s16x8;
typedef __attribute__((ext_vector_type(4))) float f32x4;
typedef __attribute__((ext_vector_type(4))) uint32_t u32x4;

#define WAITVM(N) asm volatile("s_waitcnt vmcnt(" #N ")" ::: "memory")
#define VMFENCE() do { asm volatile("" ::: "memory"); __builtin_amdgcn_sched_barrier(0); } while(0)

// ---------------- scalar helpers ----------------
__device__ __forceinline__ float dot4(const float4 a, const float4 b){
    return a.x*b.x + a.y*b.y + a.z*b.z + a.w*b.w;
}
__device__ __forceinline__ float sigm(float x){ return 1.0f/(1.0f+expf(-x)); }
__device__ __forceinline__ float leakyf(float x){ return x > 0.0f ? x : 0.01f*x; }
__device__ __forceinline__ float alphaf(float x){
    float p = 1.0f/(1.0f+expf(-x));
    return p/(1.0f-p);
}
__device__ __forceinline__ f32x4 MFMA(s16x8 a, s16x8 b, f32x4 c){
    return __builtin_amdgcn_mfma_f32_16x16x32_bf16(a, b, c, 0, 0, 0);
}

// ---------------- coherent (cross-XCD) access ----------------
__device__ __forceinline__ uint32_t cld_u32(const uint32_t* p){
    return __hip_atomic_load(p, __ATOMIC_RELAXED, __HIP_MEMORY_SCOPE_AGENT);
}
__device__ __forceinline__ uint64_t cld_u64(const uint64_t* p){
    return __hip_atomic_load(p, __ATOMIC_RELAXED, __HIP_MEMORY_SCOPE_AGENT);
}
__device__ __forceinline__ void cst_u32(uint32_t* p, uint32_t v){
    __hip_atomic_store(p, v, __ATOMIC_RELAXED, __HIP_MEMORY_SCOPE_AGENT);
}

// packed bf16 hi/lo pair
__device__ __forceinline__ uint32_t packsplit(float v){
    uint32_t u  = __float_as_uint(v);
    uint32_t hi = u & 0xFFFF0000u;
    float    lo = v - __uint_as_float(hi);
    return hi | (__float_as_uint(lo) >> 16);
}
__device__ __forceinline__ float unpackf(uint32_t w){
    return __uint_as_float(w & 0xFFFF0000u) + __uint_as_float(w << 16);
}

// ---------------- async global->LDS ----------------
__device__ __forceinline__ void stage16(const void* g, void* l){
    __builtin_amdgcn_global_load_lds(
        (const __attribute__((address_space(1))) void*)g,
        (__attribute__((address_space(3))) void*)l, 16, 0, 0);
}

// ---------------- distributed barrier: 8 counters on separate lines ----------------
__device__ __forceinline__ int bar_sum(const int* bar){
    int s = 0;
    #pragma unroll
    for (int i = 0; i < 8; i++)
        s += (int)cld_u32((const uint32_t*)(bar + i*32));
    return s;
}
// arrive + wait (gate wgs)
__device__ __forceinline__ void gbar(int* bar, int target){
    asm volatile("s_waitcnt vmcnt(0)" ::: "memory");
    __syncthreads();
    if (threadIdx.x == 0){
        __hip_atomic_fetch_add(bar + (blockIdx.x & 7)*32, 1,
                               __ATOMIC_RELAXED, __HIP_MEMORY_SCOPE_AGENT);
        while (bar_sum(bar) < target)
            __builtin_amdgcn_s_sleep(1);
    }
    __syncthreads();
}
// arrive only (encoder wgs)
__device__ __forceinline__ void gbar_arrive(int* bar){
    asm volatile("s_waitcnt vmcnt(0)" ::: "memory");
    __syncthreads();
    if (threadIdx.x == 0)
        __hip_atomic_fetch_add(bar + (blockIdx.x & 7)*32, 1,
                               __ATOMIC_RELAXED, __HIP_MEMORY_SCOPE_AGENT);
    __syncthreads();
}
// wait only (encoder wgs)
__device__ __forceinline__ void gbar_poll(const int* bar, int target){
    if (threadIdx.x == 0){
        while (bar_sum(bar) < target)
            __builtin_amdgcn_s_sleep(1);
    }
    __syncthreads();
}

// workgroup barrier flavors
__device__ __forceinline__ void wgbar(){ __builtin_amdgcn_s_barrier(); }
__device__ __forceinline__ void wgbar_lgkm(){
    asm volatile("s_waitcnt lgkmcnt(0)" ::: "memory");
    __builtin_amdgcn_s_barrier();
}

// ---------------- fragment builders ----------------
__device__ __forceinline__ void mk_frag(const uint64_t d[4], s16x8* hi, s16x8* lo){
    union { u32x4 u; s16x8 s; } H, L;
    #pragma unroll
    for (int i = 0; i < 4; i++){
        uint32_t x0 = (uint32_t)d[i], x1 = (uint32_t)(d[i] >> 32);
        H.u[i] = __builtin_amdgcn_perm(x1, x0, 0x07060302u);
        L.u[i] = __builtin_amdgcn_perm(x1, x0, 0x05040100u);
    }
    *hi = H.s; *lo = L.s;
}
__device__ __forceinline__ void pack8(const float* f, s16x8* hi, s16x8* lo){
    union { u32x4 u; s16x8 s; } H, L;
    #pragma unroll
    for (int i = 0; i < 4; i++){
        float a = f[2*i], b = f[2*i+1];
        uint32_t ua = __float_as_uint(a), ub = __float_as_uint(b);
        uint32_t ha = ua & 0xFFFF0000u, hb = ub & 0xFFFF0000u;
        H.u[i] = (ua >> 16) | hb;
        float la = a - __uint_as_float(ha), lb = b - __uint_as_float(hb);
        L.u[i] = (__float_as_uint(la) >> 16) | (__float_as_uint(lb) & 0xFFFF0000u);
    }
    *hi = H.s; *lo = L.s;
}

// ---------------- fp32 encoder block (PROLOGUE ONLY) ----------------
__device__ void enc_h_block(int e, const uint32_t* __restrict__ hsrc,
                            uint32_t* __restrict__ htil,
                            const float* __restrict__ w1, const float* __restrict__ b1,
                            const float* __restrict__ w2, const float* __restrict__ b2,
                            const float* __restrict__ w3, const float* __restrict__ b3,
                            float* smem)
{
    float* hlds = smem;
    float* t1   = smem + 4*516;
    float* t2   = t1 + 4*132;
    const int tid = threadIdx.x;
    const int r0 = e * 4;
    #pragma unroll
    for (int i = 0; i < 8; i++){
        int el = tid + i*256;
        int rr = el >> 9, k = el & 511;
        hlds[rr*516 + k] = unpackf(cld_u32(hsrc + (r0+rr)*HH + k));
    }
    __syncthreads();
    const int cc = tid & 63;
    const int rr = (tid >> 6) & 3;
    for (int cb = 0; cb < 2; cb++){
        int c = cc + cb*64;
        const float* wr = w1 + c*HH;
        const float* xr = hlds + rr*516;
        float a0 = b1[c], a1 = 0.f;
        #pragma unroll 8
        for (int k = 0; k < HH; k += 8){
            a0 += dot4(*(const float4*)(xr+k),   *(const float4*)(wr+k));
            a1 += dot4(*(const float4*)(xr+k+4), *(const float4*)(wr+k+4));
        }
        t1[rr*132 + c] = leakyf(a0 + a1);
    }
    __syncthreads();
    for (int cb = 0; cb < 2; cb++){
        int c = cc + cb*64;
        const float* wr = w2 + c*EHD;
        const float* xr = t1 + rr*132;
        float a0 = b2[c], a1 = 0.f;
        #pragma unroll 4
        for (int k = 0; k < EHD; k += 8){
            a0 += dot4(*(const float4*)(xr+k),   *(const float4*)(wr+k));
            a1 += dot4(*(const float4*)(xr+k+4), *(const float4*)(wr+k+4));
        }
        t2[rr*132 + c] = leakyf(a0 + a1);
    }
    __syncthreads();
    for (int cb = 0; cb < 8; cb++){
        int c = cc + cb*64;
        const float* wr = w3 + c*EHD;
        const float* xr = t2 + rr*132;
        float a0 = b3[c], a1 = 0.f;
        #pragma unroll 4
        for (int k = 0; k < EHD; k += 8){
            a0 += dot4(*(const float4*)(xr+k),   *(const float4*)(wr+k));
            a1 += dot4(*(const float4*)(xr+k+4), *(const float4*)(wr+k+4));
        }
        float a = alphaf(a0 + a1);
        cst_u32(htil + (r0+rr)*HH + c, packsplit(hlds[rr*516 + c] * a));
    }
    __syncthreads();
}

__global__ __launch_bounds__(256) void enc_only_kernel(
    const uint32_t* __restrict__ hsrc, uint32_t* __restrict__ htil,
    const float* __restrict__ w1, const float* __restrict__ b1,
    const float* __restrict__ w2, const float* __restrict__ b2,
    const float* __restrict__ w3, const float* __restrict__ b3)
{
    __shared__ float smem[3120];
    enc_h_block(blockIdx.x, hsrc, htil, w1, b1, w2, b2, w3, b3, smem);
}

// ---------------- x' = input * alpha_y(input): packed, [T][B][I] ----------------
__global__ __launch_bounds__(256) void ency_kernel(
    const float* __restrict__ xin, uint32_t* __restrict__ xprime,
    const float* __restrict__ w1, const float* __restrict__ b1,
    const float* __restrict__ w2, const float* __restrict__ b2,
    const float* __restrict__ w3, const float* __restrict__ b3)
{
    __shared__ float t1[32*128];
    __shared__ float t2[32*128];
    const long m0 = (long)blockIdx.x * 32;
    const int tid = threadIdx.x;
    const int cc = tid & 63;
    const int rr = tid >> 6;
    for (int cb = 0; cb < 2; cb++){
        int c = cc + cb*64;
        const float* wr = w1 + c*II;
        for (int q = 0; q < 8; q++){
            int r = rr*8 + q;
            const float* xr = xin + (m0 + r)*II;
            float a0 = b1[c], a1 = 0.f;
            #pragma unroll 8
            for (int k = 0; k < II; k += 8){
                a0 += dot4(*(const float4*)(xr+k),   *(const float4*)(wr+k));
                a1 += dot4(*(const float4*)(xr+k+4), *(const float4*)(wr+k+4));
            }
            t1[r*128 + c] = leakyf(a0 + a1);
        }
    }
    __syncthreads();
    for (int cb = 0; cb < 2; cb++){
        int c = cc + cb*64;
        const float* wr = w2 + c*EHD;
        for (int q = 0; q < 8; q++){
            int r = rr*8 + q;
            const float* xr = t1 + r*128;
            float a0 = b2[c], a1 = 0.f;
            #pragma unroll 4
            for (int k = 0; k < EHD; k += 8){
                a0 += dot4(*(const float4*)(xr+k),   *(const float4*)(wr+k));
                a1 += dot4(*(const float4*)(xr+k+4), *(const float4*)(wr+k+4));
            }
            t2[r*128 + c] = leakyf(a0 + a1);
        }
    }
    __syncthreads();
    for (int cb = 0; cb < 4; cb++){
        int c = cc + cb*64;
        const float* wr = w3 + c*EHD;
        for (int q = 0; q < 8; q++){
            int r = rr*8 + q;
            const float* xr = t2 + r*128;
            float a0 = b3[c], a1 = 0.f;
            #pragma unroll 4
            for (int k = 0; k < EHD; k += 8){
                a0 += dot4(*(const float4*)(xr+k),   *(const float4*)(wr+k));
                a1 += dot4(*(const float4*)(xr+k+4), *(const float4*)(wr+k+4));
            }
            float a = alphaf(a0 + a1);
            long m = m0 + r;                       // m = b*TT + t
            long b = m >> 11, t = m & 2047;
            xprime[((long)t*BB + b)*II + c] = packsplit(xin[m*II + c] * a);
        }
    }
}

// ---------------- gate weight packing ----------------
__global__ __launch_bounds__(64) void prep_pack_kernel(
    const float* __restrict__ Wih0, const float* __restrict__ Whh0,
    const float* __restrict__ Wih1, const float* __restrict__ Whh1,
    ushort* __restrict__ wpack)
{
    const int b = blockIdx.x;          // 128*56
    const int lane = threadIdx.x;
    const int g4 = b / 56, kts = b % 56;
    const int layer = (kts >= 24) ? 1 : 0;
    const int kt = layer ? (kts - 24) : kts;
    const int c = lane & 15;
    const int gate = c >> 2, uu = c & 3;
    const int n = gate*512 + g4*4 + uu;
    const int k = kt*32 + (lane >> 4)*8;
    const float* src;
    if (!layer){
        if (k < 256) src = Wih0 + (long)n*II + k;
        else         src = Whh0 + (long)n*HH + (k - 256);
    } else {
        if (k < 512) src = Wih1 + (long)n*HH + k;
        else         src = Whh1 + (long)n*HH + (k - 512);
    }
    ushort hi[8], lo[8];
    #pragma unroll
    for (int j = 0; j < 8; j++){
        float v = src[j];
        uint32_t u = __float_as_uint(v);
        hi[j] = (ushort)(u >> 16);
        float hf = __uint_as_float(u & 0xFFFF0000u);
        lo[j] = (ushort)(__float_as_uint(v - hf) >> 16);
    }
    long bhi = ((long)g4*7168 + kts*64 + lane) * 8;
    long blo = bhi + (long)3584*8;
    #pragma unroll
    for (int j = 0; j < 8; j++){ wpack[bhi + j] = hi[j]; wpack[blo + j] = lo[j]; }
}

// ---------------- encoder weight packing ----------------
__global__ __launch_bounds__(64) void enc_pack_kernel(
    const float* __restrict__ w1, const float* __restrict__ w2,
    const float* __restrict__ w3, ushort* __restrict__ epack)
{
    const int f = blockIdx.x;      // 0..287
    const int lane = threadIdx.x;
    const int c = lane & 15, kq = lane >> 4;
    const float* src;
    if (f < 128){
        int nt = f >> 4, kt = f & 15;
        src = w1 + (long)(nt*16 + c)*HH + kt*32 + kq*8;
    } else if (f < 160){
        int q = f - 128; int nt = q >> 2, kt = q & 3;
        src = w2 + (long)(nt*16 + c)*EHD + kt*32 + kq*8;
    } else {
        int q = f - 160; int nt = q >> 2, kt = q & 3;
        src = w3 + (long)(nt*16 + c)*EHD + kt*32 + kq*8;
    }
    long off = ((long)f*64 + lane)*8;
    #pragma unroll
    for (int j = 0; j < 8; j++){
        float v = src[j];
        uint32_t u = __float_as_uint(v);
        epack[off + j] = (ushort)(u >> 16);
        float hf = __uint_as_float(u & 0xFFFF0000u);
        epack[off + 147456 + j] = (ushort)(__float_as_uint(v - hf) >> 16);
    }
}

// ---------------- init ----------------
__global__ __launch_bounds__(256) void init_state_kernel(
    const float* __restrict__ h0, uint32_t* __restrict__ hpack, int* __restrict__ bar)
{
    int i = blockIdx.x*256 + threadIdx.x;
    hpack[i] = packsplit(h0[i]);
    if (blockIdx.x == 0 && threadIdx.x < 256) bar[threadIdx.x] = 0;
}

// ---------------- gate helpers ----------------
struct Accs { f32x4 a1, a2, b1, b2; };

// 16 atomic u64 loads (one 4-kt chunk of A)
template<int PHASE>
__device__ __forceinline__ void gate_aload4(int c, int t, int brow, int kq,
    const uint32_t* __restrict__ xp, const uint32_t* __restrict__ h0p,
    const uint32_t* __restrict__ htilp, uint64_t* d)
{
    #pragma unroll
    for (int ktl = 0; ktl < 4; ktl++){
        const int kt = c*4 + ktl;
        const uint64_t* p;
        if (PHASE == 0){
            if (kt < 8) p = (const uint64_t*)(xp + ((long)t*BB + brow)*II) + kt*16 + kq*4;
            else        p = (const uint64_t*)(htilp + (long)brow*HH) + (kt-8)*16 + kq*4;
        } else {
            if (kt < 16) p = (const uint64_t*)(h0p + (long)brow*HH) + kt*16 + kq*4;
            else         p = (const uint64_t*)(htilp + (long)brow*HH) + (kt-16)*16 + kq*4;
        }
        #pragma unroll
        for (int i=0;i<4;i++) d[ktl*4+i] = cld_u64(p+i);
    }
}

// stage one 4-kt chunk of lo-weights: wave wv stages ktl=wv, both n-groups
__device__ __forceinline__ void gate_stage4(int c, int wv, int lane, int KT0,
    const s16x8* __restrict__ wlo0, const s16x8* __restrict__ wlo1,
    char* __restrict__ wbuf)
{
    char* slot = wbuf + (c%3)*8192;
    const int ktg = KT0 + c*4 + wv;
    stage16((const char*)(wlo0 + (long)ktg*64) + lane*16, slot + (wv*2+0)*1024);
    stage16((const char*)(wlo1 + (long)ktg*64) + lane*16, slot + (wv*2+1)*1024);
}

// ---------------- gate phase: 4-kt chunks, DMA lo-weights, pipelined A ----------------
template<int PHASE>
__device__ __forceinline__ void gate_phase(
    int t, int g, int tid,
    const s16x8* __restrict__ whl, char* __restrict__ wbuf,
    const s16x8* __restrict__ wlo0, const s16x8* __restrict__ wlo1,
    const uint32_t* __restrict__ xp,
    const uint32_t* __restrict__ h0p,
    const uint32_t* __restrict__ htilp,
    const float* bsum, uint32_t* __restrict__ hdst,
    float creg[2], float hreg[2], float* __restrict__ yout)
{
    const int lane = tid & 63;
    const int wv   = tid >> 6;
    const int brow = wv*16 + (lane & 15);
    const int kq   = lane >> 4;
    constexpr int NCH = PHASE ? 8 : 6;
    constexpr int KT0 = PHASE ? 24 : 0;

    Accs ac = {};
    uint64_t dA[2][16];

    // prologue: chunks 0 and 1 (order pinned: [S(2),A(16)] x2 = 18 ops per chunk)
    gate_stage4(0, wv, lane, KT0, wlo0, wlo1, wbuf);
    VMFENCE();
    gate_aload4<PHASE>(0, t, brow, kq, xp, h0p, htilp, dA[0]);
    VMFENCE();
    gate_stage4(1, wv, lane, KT0, wlo0, wlo1, wbuf);
    VMFENCE();
    gate_aload4<PHASE>(1, t, brow, kq, xp, h0p, htilp, dA[1]);
    VMFENCE();

    #pragma unroll
    for (int c = 0; c < NCH; c++){
        if (c < NCH-1) { WAITVM(18); } else { WAITVM(0); }
        wgbar();                                  // all waves' chunk-c staging arrived
        s16x8 ah[4], al[4];
        #pragma unroll
        for (int ktl = 0; ktl < 4; ktl++)
            mk_frag(&dA[c&1][ktl*4], &ah[ktl], &al[ktl]);
        if (c + 2 < NCH){
            gate_stage4(c+2, wv, lane, KT0, wlo0, wlo1, wbuf);
            VMFENCE();
            gate_aload4<PHASE>(c+2, t, brow, kq, xp, h0p, htilp, dA[c&1]);
            VMFENCE();
        }
        const s16x8* sb = (const s16x8*)(wbuf + (c%3)*8192);
        #pragma unroll
        for (int ktl = 0; ktl < 4; ktl++){
            const int ktg = KT0 + c*4 + ktl;
            { s16x8 B1 = whl[ktg*64 + lane];
              s16x8 B2 = sb[(ktl*2+0)*64 + lane];
              ac.a1 = MFMA(ah[ktl], B1, ac.a1);
              ac.a2 = MFMA(al[ktl], B1, ac.a2);
              ac.a2 = MFMA(ah[ktl], B2, ac.a2); }
            { s16x8 B1 = whl[3584 + ktg*64 + lane];
              s16x8 B2 = sb[(ktl*2+1)*64 + lane];
              ac.b1 = MFMA(ah[ktl], B1, ac.b1);
              ac.b2 = MFMA(al[ktl], B1, ac.b2);
              ac.b2 = MFMA(ah[ktl], B2, ac.b2); }
        }
    }
    wgbar_lgkm();
    float* glds = (float*)wbuf;                  // union with staging ring (24KB >= 8.4KB)
    {
        f32x4 caf = ac.a1 + ac.a2;
        f32x4 cbf = ac.b1 + ac.b2;
        const int r0 = wv*16 + (lane>>4)*4;
        const int c16 = lane & 15;
        #pragma unroll
        for (int i = 0; i < 4; i++){
            glds[(r0+i)*33 + c16]      = caf[i];
            glds[(r0+i)*33 + 16 + c16] = cbf[i];
        }
    }
    wgbar_lgkm();
    {
        const int jloc = tid & 7, bb2 = tid >> 3;
        const int ng = jloc >> 2, uu = jloc & 3;
        const int jcol = g*8 + jloc;
        #pragma unroll
        for (int half = 0; half < 2; half++){
            int b = bb2 + half*32;
            float gi = glds[b*33 + ng*16 + 0  + uu] + bsum[0];
            float gf = glds[b*33 + ng*16 + 4  + uu] + bsum[1];
            float gg = glds[b*33 + ng*16 + 8  + uu] + bsum[2];
            float go = glds[b*33 + ng*16 + 12 + uu] + bsum[3];
            float cn = sigm(gf)*creg[half] + sigm(gi)*tanhf(gg);
            float hn = sigm(go)*tanhf(cn);
            creg[half] = cn; hreg[half] = hn;
            cst_u32(hdst + b*HH + jcol, packsplit(hn));
            if (yout) yout[((long)b*TT + t)*HH + jcol] = hn;
        }
    }
}

// ---------------- encoder staging (unchanged from R6) ----------------
__device__ __forceinline__ void enc_stage(int c, int wv, int lane,
                                          const char* __restrict__ epb, char* __restrict__ ebuf)
{
    char* slot = ebuf + (c%3)*8192;
    if (c < 8){
        #pragma unroll
        for (int ktl=0;ktl<2;ktl++)
        #pragma unroll
        for (int nt=0;nt<2;nt++)
        #pragma unroll
        for (int hl=0;hl<2;hl++){
            int f = (wv*2+nt)*16 + (c*2+ktl);
            long fidx = hl ? (288+f) : f;
            stage16(epb + fidx*1024 + lane*16, slot + (ktl*4+nt*2+hl)*1024);
        }
    } else if (c < 10){
        #pragma unroll
        for (int ktl=0;ktl<2;ktl++)
        #pragma unroll
        for (int nt=0;nt<2;nt++)
        #pragma unroll
        for (int hl=0;hl<2;hl++){
            int f = 128 + (wv*2+nt)*4 + ((c-8)*2+ktl);
            long fidx = hl ? (288+f) : f;
            stage16(epb + fidx*1024 + lane*16, slot + (ktl*4+nt*2+hl)*1024);
        }
    } else {
        int nt = c - 10;
        #pragma unroll
        for (int kt=0;kt<4;kt++)
        #pragma unroll
        for (int hl=0;hl<2;hl++){
            int f = 160 + (wv*8+nt)*4 + kt;
            long fidx = hl ? (288+f) : f;
            stage16(epb + fidx*1024 + lane*16, slot + (kt*2+hl)*1024);
        }
    }
}

// ---------------- encoder phase (MFMA, DMA-staged weights; unchanged math) ----------------
__device__ void enc_phase(
    int e, const uint32_t* __restrict__ hsrc, uint32_t* __restrict__ htil,
    const char* __restrict__ epb, char* __restrict__ ebuf,
    const float bias1[2], const float bias2[2], const float bias3[8],
    float* __restrict__ t1, float* __restrict__ t2)
{
    const int tid = threadIdx.x;
    const int lane = tid & 63, wv = tid >> 6;
    const int c16 = lane & 15, kq = lane >> 4;
    const int r0 = e * 16;

    uint32_t hv[32];
    #pragma unroll
    for (int nt=0;nt<8;nt++)
      #pragma unroll
      for (int i=0;i<4;i++)
        hv[nt*4+i] = cld_u32(hsrc + (long)(r0+kq*4+i)*HH + wv*128 + nt*16 + c16);
    VMFENCE();

    const uint64_t* hp = (const uint64_t*)(hsrc + (long)(r0 + c16)*HH) + kq*4;
    uint64_t dA[32];
    #pragma unroll
    for (int kt=0;kt<8;kt++)
      #pragma unroll
      for (int i=0;i<4;i++)
        dA[kt*4+i] = cld_u64(hp + kt*16 + i);
    VMFENCE();

    enc_stage(0, wv, lane, epb, ebuf);
    VMFENCE();
    enc_stage(1, wv, lane, epb, ebuf);
    VMFENCE();
    WAITVM(16);
    s16x8 ah1[8], al1[8], ah2[8], al2[8];
    #pragma unroll
    for (int kt=0;kt<8;kt++) mk_frag(&dA[kt*4], &ah1[kt], &al1[kt]);
    #pragma unroll
    for (int kt=0;kt<8;kt++)
      #pragma unroll
      for (int i=0;i<4;i++)
        dA[kt*4+i] = cld_u64(hp + (kt+8)*16 + i);
    VMFENCE();

    f32x4 p1[2] = {{0,0,0,0},{0,0,0,0}};
    f32x4 p2[2] = {{0,0,0,0},{0,0,0,0}};
    #pragma unroll
    for (int c=0;c<8;c++){
        if (c < 2) { WAITVM(40); } else { WAITVM(8); }
        const s16x8* sb = (const s16x8*)(ebuf + (c%3)*8192);
        #pragma unroll
        for (int ktl=0;ktl<2;ktl++){
            const int kt = c*2 + ktl;
            s16x8 ah = (kt<8) ? ah1[kt&7] : ah2[kt&7];
            s16x8 al = (kt<8) ? al1[kt&7] : al2[kt&7];
            #pragma unroll
            for (int nt=0;nt<2;nt++){
                s16x8 bh = sb[(ktl*4+nt*2+0)*64 + lane];
                s16x8 bl = sb[(ktl*4+nt*2+1)*64 + lane];
                p1[nt] = MFMA(ah, bh, p1[nt]);
                p2[nt] = MFMA(al, bh, p2[nt]);
                p2[nt] = MFMA(ah, bl, p2[nt]);
            }
        }
        enc_stage(c+2, wv, lane, epb, ebuf);
        VMFENCE();
        if (c == 3){
            #pragma unroll
            for (int kt=0;kt<8;kt++) mk_frag(&dA[kt*4], &ah2[kt], &al2[kt]);
        }
    }
    #pragma unroll
    for (int nt=0;nt<2;nt++){
        f32x4 cc = p1[nt] + p2[nt];
        const int n = wv*32 + nt*16 + c16;
        #pragma unroll
        for (int i=0;i<4;i++) t1[(kq*4+i)*132 + n] = leakyf(cc[i] + bias1[nt]);
    }
    wgbar_lgkm();
    s16x8 a2h[4], a2l[4];
    #pragma unroll
    for (int kt=0;kt<4;kt++) pack8(t1 + c16*132 + kt*32 + kq*8, &a2h[kt], &a2l[kt]);
    f32x4 q1[2] = {{0,0,0,0},{0,0,0,0}};
    f32x4 q2[2] = {{0,0,0,0},{0,0,0,0}};
    #pragma unroll
    for (int c=8;c<10;c++){
        WAITVM(8);
        const s16x8* sb = (const s16x8*)(ebuf + (c%3)*8192);
        #pragma unroll
        for (int ktl=0;ktl<2;ktl++){
            const int kt = (c-8)*2 + ktl;
            #pragma unroll
            for (int nt=0;nt<2;nt++){
                s16x8 bh = sb[(ktl*4+nt*2+0)*64 + lane];
                s16x8 bl = sb[(ktl*4+nt*2+1)*64 + lane];
                q1[nt] = MFMA(a2h[kt], bh, q1[nt]);
                q2[nt] = MFMA(a2l[kt], bh, q2[nt]);
                q2[nt] = MFMA(a2h[kt], bl, q2[nt]);
            }
        }
        enc_stage(c+2, wv, lane, epb, ebuf);
        VMFENCE();
    }
    #pragma unroll
    for (int nt=0;nt<2;nt++){
        f32x4 cc = q1[nt] + q2[nt];
        const int n = wv*32 + nt*16 + c16;
        #pragma unroll
        for (int i=0;i<4;i++) t2[(kq*4+i)*132 + n] = leakyf(cc[i] + bias2[nt]);
    }
    wgbar_lgkm();
    s16x8 a3h[4], a3l[4];
    #pragma unroll
    for (int kt=0;kt<4;kt++) pack8(t2 + c16*132 + kt*32 + kq*8, &a3h[kt], &a3l[kt]);
    float av[8][4];
    #pragma unroll
    for (int c=10;c<18;c++){
        if (c < 17) { WAITVM(8); } else { WAITVM(0); }
        const int nt = c - 10;
        const s16x8* sb = (const s16x8*)(ebuf + (c%3)*8192);
        f32x4 s1 = {0,0,0,0}, s2 = {0,0,0,0};
        #pragma unroll
        for (int kt=0;kt<4;kt++){
            s16x8 bh = sb[(kt*2+0)*64 + lane];
            s16x8 bl = sb[(kt*2+1)*64 + lane];
            s1 = MFMA(a3h[kt], bh, s1);
            s2 = MFMA(a3l[kt], bh, s2);
            s2 = MFMA(a3h[kt], bl, s2);
        }
        f32x4 cc = s1 + s2;
        #pragma unroll
        for (int i=0;i<4;i++) av[nt][i] = alphaf(cc[i] + bias3[nt]);
        if (c + 2 < 18){
            enc_stage(c+2, wv, lane, epb, ebuf);
            VMFENCE();
        }
    }
    #pragma unroll
    for (int nt=0;nt<8;nt++)
      #pragma unroll
      for (int i=0;i<4;i++){
        const int row = r0 + kq*4 + i;
        const int n = wv*128 + nt*16 + c16;
        cst_u32(htil + (long)row*HH + n, packsplit(unpackf(hv[nt*4+i]) * av[nt][i]));
      }
}

// ---------------- persistent kernel ----------------
// wgs 0..63: gates. wgs 64..67: enc h~1 (arrive odd barriers). wgs 68..71: enc h~0 (arrive even).
__global__ __launch_bounds__(256, 1) void persistent_kernel(
    const uint32_t* __restrict__ xp,
    uint32_t* __restrict__ hpack,
    const ushort* __restrict__ wpack,
    const ushort* __restrict__ epack,
    const float* __restrict__ c0in,
    const float* __restrict__ bih0, const float* __restrict__ bhh0,
    const float* __restrict__ bih1, const float* __restrict__ bhh1,
    const float* __restrict__ ehb1, const float* __restrict__ ehb2,
    const float* __restrict__ ehb3,
    float* __restrict__ out, int* __restrict__ bar)
{
    extern __shared__ char smem_raw[];
    const int wg = blockIdx.x, tid = threadIdx.x;
    uint32_t* h0p = hpack;
    uint32_t* h1p = hpack + 32768;
    uint32_t* ht0 = hpack + 65536;
    uint32_t* ht1 = hpack + 98304;

    if (wg >= NGATE){
        // -------- encoder wg --------
        char* ebuf = smem_raw + (tid>>6)*24576;       // per-wave 3x8KB ring
        float* t1 = (float*)(smem_raw + 98304);       // [16][132]
        float* t2 = t1 + 16*132;
        const bool is_h1 = (wg < NGATE + 4);
        const int e = (wg - NGATE) & 3;               // 0..3 within group
        const char* epb = (const char*)epack;
        const int lane = tid & 63, wv = tid >> 6, c16 = lane & 15;
        float bias1[2], bias2[2], bias3[8];
        #pragma unroll
        for (int nt = 0; nt < 2; nt++){
            bias1[nt] = ehb1[wv*32 + nt*16 + c16];
            bias2[nt] = ehb2[wv*32 + nt*16 + c16];
        }
        #pragma unroll
        for (int nt = 0; nt < 8; nt++)
            bias3[nt] = ehb3[wv*128 + nt*16 + c16];
        WAITVM(0);
        __syncthreads();
        if (is_h1){
            for (int t = 0; t < TT; t++){
                gbar_poll(bar, ARRV*(2*t));           // h1^{t-1} ready (t=0: trivial)
                enc_phase(e, h1p, ht1, epb, ebuf, bias1, bias2, bias3, t1, t2);
                gbar_arrive(bar);                      // counts toward barrier 2t+1
            }
        } else {
            for (int t = 0; t < TT; t++){
                gbar_poll(bar, ARRV*(2*t+1));         // h0^t ready
                enc_phase(e, h0p, ht0, epb, ebuf, bias1, bias2, bias3, t1, t2);
                gbar_arrive(bar);                      // counts toward barrier 2t+2
            }
        }
        return;
    }
    // -------- gate wg: 32 gate-columns --------
    s16x8* whl = (s16x8*)smem_raw;                   // 7168 frags = 114688 B
    char*  wbuf = smem_raw + 114688;                 // 3x8KB ring (union glds)
    const int g = wg;
    const s16x8* wp = (const s16x8*)wpack;
    for (int i = tid; i < 7168; i += 256){
        int ng = (i >= 3584) ? 1 : 0;
        int r  = i - ng*3584;
        whl[i] = wp[(long)(2*g+ng)*7168 + r];
    }
    const s16x8* wlo0 = wp + (long)(2*g  )*7168 + 3584;
    const s16x8* wlo1 = wp + (long)(2*g+1)*7168 + 3584;

    const int jloc = tid & 7, bb2 = tid >> 3;
    const int jcol = g*8 + jloc;
    float bsum0[4], bsum1[4];
    #pragma unroll
    for (int q = 0; q < 4; q++){
        int n = q*512 + jcol;
        bsum0[q] = bih0[n] + bhh0[n];
        bsum1[q] = bih1[n] + bhh1[n];
    }
    float c0reg[2], c1reg[2], h0reg[2] = {0.f,0.f}, h1reg[2] = {0.f,0.f};
    #pragma unroll
    for (int half = 0; half < 2; half++){
        int b = bb2 + half*32;
        c0reg[half] = c0in[b*HH + jcol];
        c1reg[half] = c0in[32768 + b*HH + jcol];
    }
    WAITVM(0);
    __syncthreads();

    for (int t = 0; t < TT; t++){
        gate_phase<0>(t, g, tid, whl, wbuf, wlo0, wlo1,
                      xp, h0p, ht0, bsum0, h0p, c0reg, h0reg, nullptr);
        gbar(bar, ARRV*(2*t+1));
        gate_phase<1>(t, g, tid, whl, wbuf, wlo0, wlo1,
                      xp, h0p, ht1, bsum1, h1p, c1reg, h1reg, out);
        gbar(bar, ARRV*(2*t+2));
    }
    const long base = (long)BB*TT*HH;
    #pragma unroll
    for (int half = 0; half < 2; half++){
        int b = bb2 + half*32;
        out[base +                  b*HH + jcol] = h0reg[half];
        out[base + 32768          + b*HH + jcol] = h1reg[half];
        out[base + 65536          + b*HH + jcol] = c0reg[half];
        out[base + 65536 + 32768  + b*HH + jcol] = c1reg[half];
    }
}

// ---------------- launch ----------------
extern "C" void kernel_launch(void* const* d_in, const int* in_sizes, int n_in,
                              void* d_out, int out_size, void* d_ws, size_t ws_size,
                              hipStream_t stream)
{
    const float* input = (const float*)d_in[0];
    const float* h0in  = (const float*)d_in[1];
    const float* c0in  = (const float*)d_in[2];
    const float* Wih0  = (const float*)d_in[3];
    const float* Whh0  = (const float*)d_in[4];
    const float* bih0  = (const float*)d_in[5];
    const float* bhh0  = (const float*)d_in[6];
    const float* Wih1  = (const float*)d_in[7];
    const float* Whh1  = (const float*)d_in[8];
    const float* bih1  = (const float*)d_in[9];
    const float* bhh1  = (const float*)d_in[10];
    const float* eyw1  = (const float*)d_in[11];
    const float* eyb1  = (const float*)d_in[12];
    const float* eyw2  = (const float*)d_in[13];
    const float* eyb2  = (const float*)d_in[14];
    const float* eyw3  = (const float*)d_in[15];
    const float* eyb3  = (const float*)d_in[16];
    const float* ehw1  = (const float*)d_in[17];
    const float* ehb1  = (const float*)d_in[18];
    const float* ehw2  = (const float*)d_in[19];
    const float* ehb2  = (const float*)d_in[20];
    const float* ehw3  = (const float*)d_in[21];
    const float* ehb3  = (const float*)d_in[22];

    float* out = (float*)d_out;
    float* ws  = (float*)d_ws;

    // ws layout (4B units)
    uint32_t* xprime = (uint32_t*)ws;                  // [T][B][I] packed
    uint32_t* hpack  = (uint32_t*)(ws + 33554432);     // h0,h1,ht0,ht1
    int*      bar    = (int*)(ws + 33685504);          // 8 counters, 128B apart
    ushort*   wpack  = (ushort*)(ws + 33751104);       // 14,680,064 B
    ushort*   epack  = (ushort*)(ws + 37421120);       // 589,824 B

    hipFuncSetAttribute((const void*)persistent_kernel,
                        hipFuncAttributeMaxDynamicSharedMemorySize, 139264);

    init_state_kernel<<<256, 256, 0, stream>>>(h0in, hpack, bar);
    prep_pack_kernel<<<128*56, 64, 0, stream>>>(Wih0, Whh0, Wih1, Whh1, wpack);
    enc_pack_kernel<<<288, 64, 0, stream>>>(ehw1, ehw2, ehw3, epack);
    ency_kernel<<<4096, 256, 0, stream>>>(input, xprime,
                                          eyw1, eyb1, eyw2, eyb2, eyw3, eyb3);
    enc_only_kernel<<<16, 256, 0, stream>>>(hpack, hpack + 65536,
                                            ehw1, ehb1, ehw2, ehb2, ehw3, ehb3);
    persistent_kernel<<<NWG, 256, 139264, stream>>>(
        xprime, hpack, wpack, epack, c0in,
        bih0, bhh0, bih1, bhh1,
        ehb1, ehb2, ehb3,
        out, bar);
}

// Round 8
// 93892.957 us; speedup vs baseline: 1.2630x; 1.2630x over previous
//
#include <hip/hip_runtime.h>
#include <math.h>
#include <stdint.h>

#define TT 2048
#define BB 64
#define II 256
#define HH 512
#define EHD 128
#define NGATE 64
#define NWG 68

typedef __attribute__((ext_vector_type(8))) short s16x8;
typedef __attribute__((ext_vector_type(4))) float f32x4;
typedef __attribute__((ext_vector_type(4))) uint32_t u32x4;

#define WAITVM(N) asm volatile("s_waitcnt vmcnt(" #N ")" ::: "memory")
#define VMFENCE() do { asm volatile("" ::: "memory"); __builtin_amdgcn_sched_barrier(0); } while(0)

// ---------------- scalar helpers ----------------
__device__ __forceinline__ float dot4(const float4 a, const float4 b){
    return a.x*b.x + a.y*b.y + a.z*b.z + a.w*b.w;
}
__device__ __forceinline__ float sigm(float x){ return 1.0f/(1.0f+expf(-x)); }
__device__ __forceinline__ float leakyf(float x){ return x > 0.0f ? x : 0.01f*x; }
__device__ __forceinline__ float alphaf(float x){
    float p = 1.0f/(1.0f+expf(-x));
    return p/(1.0f-p);
}
__device__ __forceinline__ f32x4 MFMA(s16x8 a, s16x8 b, f32x4 c){
    return __builtin_amdgcn_mfma_f32_16x16x32_bf16(a, b, c, 0, 0, 0);
}

// ---------------- coherent (cross-XCD) access ----------------
__device__ __forceinline__ uint32_t cld_u32(const uint32_t* p){
    return __hip_atomic_load(p, __ATOMIC_RELAXED, __HIP_MEMORY_SCOPE_AGENT);
}
__device__ __forceinline__ uint64_t cld_u64(const uint64_t* p){
    return __hip_atomic_load(p, __ATOMIC_RELAXED, __HIP_MEMORY_SCOPE_AGENT);
}
__device__ __forceinline__ void cst_u32(uint32_t* p, uint32_t v){
    __hip_atomic_store(p, v, __ATOMIC_RELAXED, __HIP_MEMORY_SCOPE_AGENT);
}

// packed bf16 hi/lo pair
__device__ __forceinline__ uint32_t packsplit(float v){
    uint32_t u  = __float_as_uint(v);
    uint32_t hi = u & 0xFFFF0000u;
    float    lo = v - __uint_as_float(hi);
    return hi | (__float_as_uint(lo) >> 16);
}
__device__ __forceinline__ float unpackf(uint32_t w){
    return __uint_as_float(w & 0xFFFF0000u) + __uint_as_float(w << 16);
}

// ---------------- async global->LDS ----------------
__device__ __forceinline__ void stage16(const void* g, void* l){
    __builtin_amdgcn_global_load_lds(
        (const __attribute__((address_space(1))) void*)g,
        (__attribute__((address_space(3))) void*)l, 16, 0, 0);
}

// ---------------- release-flag barrier ----------------
// Arrivals: 8 counter lines (<=9 RMWs each, never polled except by wg 0).
// wg 0 aggregates: polls sum of 8 lines until NWG*epoch, then writes the
// monotone release flag (9th line). Everyone else polls ONLY the flag —
// read-only traffic that cannot queue ahead of arrival RMWs.
__device__ __forceinline__ int bar_sum(const int* bar){
    int s = 0;
    #pragma unroll
    for (int i = 0; i < 8; i++)
        s += (int)cld_u32((const uint32_t*)(bar + i*32));
    return s;
}
__device__ __forceinline__ void gbar(int* bar, int epoch){
    asm volatile("s_waitcnt vmcnt(0)" ::: "memory");   // this wg's sc1 stores ack'd
    __syncthreads();
    if (threadIdx.x == 0){
        __hip_atomic_fetch_add(bar + (blockIdx.x & 7)*32, 1,
                               __ATOMIC_RELAXED, __HIP_MEMORY_SCOPE_AGENT);
        if (blockIdx.x == 0){
            const int target = NWG * epoch;
            while (bar_sum(bar) < target)
                __builtin_amdgcn_s_sleep(1);
            cst_u32((uint32_t*)(bar + 8*32), (uint32_t)epoch);   // release
        } else {
            while ((int)cld_u32((const uint32_t*)(bar + 8*32)) < epoch)
                __builtin_amdgcn_s_sleep(2);
        }
    }
    __syncthreads();
}

// workgroup barrier flavors (avoid __syncthreads' vmcnt(0) drain)
__device__ __forceinline__ void wgbar(){ __builtin_amdgcn_s_barrier(); }
__device__ __forceinline__ void wgbar_lgkm(){
    asm volatile("s_waitcnt lgkmcnt(0)" ::: "memory");
    __builtin_amdgcn_s_barrier();
}

// ---------------- fragment builders ----------------
__device__ __forceinline__ void mk_frag(const uint64_t d[4], s16x8* hi, s16x8* lo){
    union { u32x4 u; s16x8 s; } H, L;
    #pragma unroll
    for (int i = 0; i < 4; i++){
        uint32_t x0 = (uint32_t)d[i], x1 = (uint32_t)(d[i] >> 32);
        H.u[i] = __builtin_amdgcn_perm(x1, x0, 0x07060302u);
        L.u[i] = __builtin_amdgcn_perm(x1, x0, 0x05040100u);
    }
    *hi = H.s; *lo = L.s;
}
__device__ __forceinline__ void pack8(const float* f, s16x8* hi, s16x8* lo){
    union { u32x4 u; s16x8 s; } H, L;
    #pragma unroll
    for (int i = 0; i < 4; i++){
        float a = f[2*i], b = f[2*i+1];
        uint32_t ua = __float_as_uint(a), ub = __float_as_uint(b);
        uint32_t ha = ua & 0xFFFF0000u, hb = ub & 0xFFFF0000u;
        H.u[i] = (ua >> 16) | hb;
        float la = a - __uint_as_float(ha), lb = b - __uint_as_float(hb);
        L.u[i] = (__float_as_uint(la) >> 16) | (__float_as_uint(lb) & 0xFFFF0000u);
    }
    *hi = H.s; *lo = L.s;
}

// ---------------- fp32 encoder block (PROLOGUE ONLY) ----------------
__device__ void enc_h_block(int e, const uint32_t* __restrict__ hsrc,
                            uint32_t* __restrict__ htil,
                            const float* __restrict__ w1, const float* __restrict__ b1,
                            const float* __restrict__ w2, const float* __restrict__ b2,
                            const float* __restrict__ w3, const float* __restrict__ b3,
                            float* smem)
{
    float* hlds = smem;              // [4][516]
    float* t1   = smem + 4*516;      // [4][132]
    float* t2   = t1 + 4*132;        // [4][132]
    const int tid = threadIdx.x;
    const int r0 = e * 4;
    #pragma unroll
    for (int i = 0; i < 8; i++){
        int el = tid + i*256;
        int rr = el >> 9, k = el & 511;
        hlds[rr*516 + k] = unpackf(cld_u32(hsrc + (r0+rr)*HH + k));
    }
    __syncthreads();
    const int cc = tid & 63;
    const int rr = (tid >> 6) & 3;
    for (int cb = 0; cb < 2; cb++){
        int c = cc + cb*64;
        const float* wr = w1 + c*HH;
        const float* xr = hlds + rr*516;
        float a0 = b1[c], a1 = 0.f;
        #pragma unroll 8
        for (int k = 0; k < HH; k += 8){
            a0 += dot4(*(const float4*)(xr+k),   *(const float4*)(wr+k));
            a1 += dot4(*(const float4*)(xr+k+4), *(const float4*)(wr+k+4));
        }
        t1[rr*132 + c] = leakyf(a0 + a1);
    }
    __syncthreads();
    for (int cb = 0; cb < 2; cb++){
        int c = cc + cb*64;
        const float* wr = w2 + c*EHD;
        const float* xr = t1 + rr*132;
        float a0 = b2[c], a1 = 0.f;
        #pragma unroll 4
        for (int k = 0; k < EHD; k += 8){
            a0 += dot4(*(const float4*)(xr+k),   *(const float4*)(wr+k));
            a1 += dot4(*(const float4*)(xr+k+4), *(const float4*)(wr+k+4));
        }
        t2[rr*132 + c] = leakyf(a0 + a1);
    }
    __syncthreads();
    for (int cb = 0; cb < 8; cb++){
        int c = cc + cb*64;
        const float* wr = w3 + c*EHD;
        const float* xr = t2 + rr*132;
        float a0 = b3[c], a1 = 0.f;
        #pragma unroll 4
        for (int k = 0; k < EHD; k += 8){
            a0 += dot4(*(const float4*)(xr+k),   *(const float4*)(wr+k));
            a1 += dot4(*(const float4*)(xr+k+4), *(const float4*)(wr+k+4));
        }
        float a = alphaf(a0 + a1);
        cst_u32(htil + (r0+rr)*HH + c, packsplit(hlds[rr*516 + c] * a));
    }
    __syncthreads();
}

__global__ __launch_bounds__(256) void enc_only_kernel(
    const uint32_t* __restrict__ hsrc, uint32_t* __restrict__ htil,
    const float* __restrict__ w1, const float* __restrict__ b1,
    const float* __restrict__ w2, const float* __restrict__ b2,
    const float* __restrict__ w3, const float* __restrict__ b3)
{
    __shared__ float smem[3120];
    enc_h_block(blockIdx.x, hsrc, htil, w1, b1, w2, b2, w3, b3, smem);
}

// ---------------- x' = input * alpha_y(input): packed, [T][B][I] ----------------
__global__ __launch_bounds__(256) void ency_kernel(
    const float* __restrict__ xin, uint32_t* __restrict__ xprime,
    const float* __restrict__ w1, const float* __restrict__ b1,
    const float* __restrict__ w2, const float* __restrict__ b2,
    const float* __restrict__ w3, const float* __restrict__ b3)
{
    __shared__ float t1[32*128];
    __shared__ float t2[32*128];
    const long m0 = (long)blockIdx.x * 32;
    const int tid = threadIdx.x;
    const int cc = tid & 63;
    const int rr = tid >> 6;
    for (int cb = 0; cb < 2; cb++){
        int c = cc + cb*64;
        const float* wr = w1 + c*II;
        for (int q = 0; q < 8; q++){
            int r = rr*8 + q;
            const float* xr = xin + (m0 + r)*II;
            float a0 = b1[c], a1 = 0.f;
            #pragma unroll 8
            for (int k = 0; k < II; k += 8){
                a0 += dot4(*(const float4*)(xr+k),   *(const float4*)(wr+k));
                a1 += dot4(*(const float4*)(xr+k+4), *(const float4*)(wr+k+4));
            }
            t1[r*128 + c] = leakyf(a0 + a1);
        }
    }
    __syncthreads();
    for (int cb = 0; cb < 2; cb++){
        int c = cc + cb*64;
        const float* wr = w2 + c*EHD;
        for (int q = 0; q < 8; q++){
            int r = rr*8 + q;
            const float* xr = t1 + r*128;
            float a0 = b2[c], a1 = 0.f;
            #pragma unroll 4
            for (int k = 0; k < EHD; k += 8){
                a0 += dot4(*(const float4*)(xr+k),   *(const float4*)(wr+k));
                a1 += dot4(*(const float4*)(xr+k+4), *(const float4*)(wr+k+4));
            }
            t2[r*128 + c] = leakyf(a0 + a1);
        }
    }
    __syncthreads();
    for (int cb = 0; cb < 4; cb++){
        int c = cc + cb*64;
        const float* wr = w3 + c*EHD;
        for (int q = 0; q < 8; q++){
            int r = rr*8 + q;
            const float* xr = t2 + r*128;
            float a0 = b3[c], a1 = 0.f;
            #pragma unroll 4
            for (int k = 0; k < EHD; k += 8){
                a0 += dot4(*(const float4*)(xr+k),   *(const float4*)(wr+k));
                a1 += dot4(*(const float4*)(xr+k+4), *(const float4*)(wr+k+4));
            }
            float a = alphaf(a0 + a1);
            long m = m0 + r;                       // m = b*TT + t
            long b = m >> 11, t = m & 2047;
            xprime[((long)t*BB + b)*II + c] = packsplit(xin[m*II + c] * a);
        }
    }
}

// ---------------- gate weight packing ----------------
__global__ __launch_bounds__(64) void prep_pack_kernel(
    const float* __restrict__ Wih0, const float* __restrict__ Whh0,
    const float* __restrict__ Wih1, const float* __restrict__ Whh1,
    ushort* __restrict__ wpack)
{
    const int b = blockIdx.x;          // 128*56
    const int lane = threadIdx.x;
    const int g4 = b / 56, kts = b % 56;
    const int layer = (kts >= 24) ? 1 : 0;
    const int kt = layer ? (kts - 24) : kts;
    const int c = lane & 15;
    const int gate = c >> 2, uu = c & 3;
    const int n = gate*512 + g4*4 + uu;
    const int k = kt*32 + (lane >> 4)*8;
    const float* src;
    if (!layer){
        if (k < 256) src = Wih0 + (long)n*II + k;
        else         src = Whh0 + (long)n*HH + (k - 256);
    } else {
        if (k < 512) src = Wih1 + (long)n*HH + k;
        else         src = Whh1 + (long)n*HH + (k - 512);
    }
    ushort hi[8], lo[8];
    #pragma unroll
    for (int j = 0; j < 8; j++){
        float v = src[j];
        uint32_t u = __float_as_uint(v);
        hi[j] = (ushort)(u >> 16);
        float hf = __uint_as_float(u & 0xFFFF0000u);
        lo[j] = (ushort)(__float_as_uint(v - hf) >> 16);
    }
    long bhi = ((long)g4*7168 + kts*64 + lane) * 8;
    long blo = bhi + (long)3584*8;
    #pragma unroll
    for (int j = 0; j < 8; j++){ wpack[bhi + j] = hi[j]; wpack[blo + j] = lo[j]; }
}

// ---------------- encoder weight packing ----------------
__global__ __launch_bounds__(64) void enc_pack_kernel(
    const float* __restrict__ w1, const float* __restrict__ w2,
    const float* __restrict__ w3, ushort* __restrict__ epack)
{
    const int f = blockIdx.x;      // 0..287
    const int lane = threadIdx.x;
    const int c = lane & 15, kq = lane >> 4;
    const float* src;
    if (f < 128){
        int nt = f >> 4, kt = f & 15;
        src = w1 + (long)(nt*16 + c)*HH + kt*32 + kq*8;
    } else if (f < 160){
        int q = f - 128; int nt = q >> 2, kt = q & 3;
        src = w2 + (long)(nt*16 + c)*EHD + kt*32 + kq*8;
    } else {
        int q = f - 160; int nt = q >> 2, kt = q & 3;
        src = w3 + (long)(nt*16 + c)*EHD + kt*32 + kq*8;
    }
    long off = ((long)f*64 + lane)*8;
    #pragma unroll
    for (int j = 0; j < 8; j++){
        float v = src[j];
        uint32_t u = __float_as_uint(v);
        epack[off + j] = (ushort)(u >> 16);
        float hf = __uint_as_float(u & 0xFFFF0000u);
        epack[off + 147456 + j] = (ushort)(__float_as_uint(v - hf) >> 16);
    }
}

// ---------------- init ----------------
__global__ __launch_bounds__(256) void init_state_kernel(
    const float* __restrict__ h0, uint32_t* __restrict__ hpack, int* __restrict__ bar)
{
    int i = blockIdx.x*256 + threadIdx.x;
    hpack[i] = packsplit(h0[i]);
    if (i < 320) bar[i] = 0;        // 8 arrival lines + release flag line
}

// ---------------- gate helpers ----------------
struct Accs { f32x4 a1, a2, b1, b2; };

// all-atomic A loads: exactly 8 non-mergeable VM ops per call
template<int PHASE>
__device__ __forceinline__ void gate_aload(int c, int t, int brow, int kq,
    const uint32_t* __restrict__ xp, const uint32_t* __restrict__ h0p,
    const uint32_t* __restrict__ htilp, uint64_t* d)
{
    #pragma unroll
    for (int ktl = 0; ktl < 2; ktl++){
        const int kt = c*2 + ktl;
        const uint64_t* p;
        if (PHASE == 0){
            if (kt < 8) p = (const uint64_t*)(xp + ((long)t*BB + brow)*II) + kt*16 + kq*4;
            else        p = (const uint64_t*)(htilp + (long)brow*HH) + (kt-8)*16 + kq*4;
        } else {
            if (kt < 16) p = (const uint64_t*)(h0p + (long)brow*HH) + kt*16 + kq*4;
            else         p = (const uint64_t*)(htilp + (long)brow*HH) + (kt-16)*16 + kq*4;
        }
        #pragma unroll
        for (int i=0;i<4;i++) d[ktl*4+i] = cld_u64(p+i);
    }
}

// ---------------- gate phase: DMA-staged lo-weights, pipelined A ----------------
template<int PHASE>
__device__ __forceinline__ void gate_phase(
    int t, int g, int tid,
    const s16x8* __restrict__ whl, char* __restrict__ wbuf,
    const s16x8* __restrict__ wlo0, const s16x8* __restrict__ wlo1,
    const uint32_t* __restrict__ xp,
    const uint32_t* __restrict__ h0p,
    const uint32_t* __restrict__ htilp,
    const float* bsum, uint32_t* __restrict__ hdst,
    float creg[2], float hreg[2], float* __restrict__ yout)
{
    const int lane = tid & 63;
    const int wv   = tid >> 6;
    const int brow = wv*16 + (lane & 15);
    const int kq   = lane >> 4;
    constexpr int NCH = PHASE ? 16 : 12;
    constexpr int KT0 = PHASE ? 24 : 0;

    const int sktl = wv >> 1, sng = wv & 1;          // per-wave staging role
    const s16x8* swsrc = sng ? wlo1 : wlo0;
    const int sfi = sktl*2 + sng;

    Accs ac = {};
    uint64_t dA[2][8];

    // prologue: S0, A0, S1, A1 — order pinned so WAITVM counts hold
    stage16((const char*)(swsrc + (KT0 + 0 + sktl)*64) + lane*16, wbuf + 0*4096 + sfi*1024);
    VMFENCE();
    gate_aload<PHASE>(0, t, brow, kq, xp, h0p, htilp, dA[0]);
    VMFENCE();
    stage16((const char*)(swsrc + (KT0 + 2 + sktl)*64) + lane*16, wbuf + 1*4096 + sfi*1024);
    VMFENCE();
    gate_aload<PHASE>(1, t, brow, kq, xp, h0p, htilp, dA[1]);
    VMFENCE();

    #pragma unroll
    for (int c = 0; c < NCH; c++){
        // queue per iter (pinned): [S, A(8)] = 9 ops; drain exactly the
        // iteration issued two ago -> slot c + dA[c&1] arrived.
        if (c < NCH-1) { WAITVM(9); } else { WAITVM(0); }
        wgbar();                                      // all waves' S_c arrived
        s16x8 ah0, al0, ah1, al1;
        mk_frag(&dA[c&1][0], &ah0, &al0);
        mk_frag(&dA[c&1][4], &ah1, &al1);
        if (c + 2 < NCH){
            stage16((const char*)(swsrc + (KT0 + (c+2)*2 + sktl)*64) + lane*16,
                    wbuf + ((c+2)%3)*4096 + sfi*1024);
            VMFENCE();
            gate_aload<PHASE>(c+2, t, brow, kq, xp, h0p, htilp, dA[c&1]);
            VMFENCE();
        }
        const s16x8* sb = (const s16x8*)(wbuf + (c%3)*4096);
        #pragma unroll
        for (int ktl = 0; ktl < 2; ktl++){
            const int ktg = KT0 + c*2 + ktl;
            s16x8 ah = ktl ? ah1 : ah0;
            s16x8 al = ktl ? al1 : al0;
            { s16x8 B1 = whl[ktg*64 + lane];
              s16x8 B2 = sb[(ktl*2+0)*64 + lane];
              ac.a1 = MFMA(ah, B1, ac.a1);
              ac.a2 = MFMA(al, B1, ac.a2);
              ac.a2 = MFMA(ah, B2, ac.a2); }
            { s16x8 B1 = whl[3584 + ktg*64 + lane];
              s16x8 B2 = sb[(ktl*2+1)*64 + lane];
              ac.b1 = MFMA(ah, B1, ac.b1);
              ac.b2 = MFMA(al, B1, ac.b2);
              ac.b2 = MFMA(ah, B2, ac.b2); }
        }
    }
    wgbar_lgkm();                                    // all slot reads done
    float* glds = (float*)wbuf;                      // union with staging ring
    {
        f32x4 caf = ac.a1 + ac.a2;
        f32x4 cbf = ac.b1 + ac.b2;
        const int r0 = wv*16 + (lane>>4)*4;
        const int c16 = lane & 15;
        #pragma unroll
        for (int i = 0; i < 4; i++){
            glds[(r0+i)*33 + c16]      = caf[i];
            glds[(r0+i)*33 + 16 + c16] = cbf[i];
        }
    }
    wgbar_lgkm();
    {
        const int jloc = tid & 7, bb2 = tid >> 3;
        const int ng = jloc >> 2, uu = jloc & 3;
        const int jcol = g*8 + jloc;
        #pragma unroll
        for (int half = 0; half < 2; half++){
            int b = bb2 + half*32;
            float gi = glds[b*33 + ng*16 + 0  + uu] + bsum[0];
            float gf = glds[b*33 + ng*16 + 4  + uu] + bsum[1];
            float gg = glds[b*33 + ng*16 + 8  + uu] + bsum[2];
            float go = glds[b*33 + ng*16 + 12 + uu] + bsum[3];
            float cn = sigm(gf)*creg[half] + sigm(gi)*tanhf(gg);
            float hn = sigm(go)*tanhf(cn);
            creg[half] = cn; hreg[half] = hn;
            cst_u32(hdst + b*HH + jcol, packsplit(hn));
            if (yout) yout[((long)b*TT + t)*HH + jcol] = hn;
        }
    }
}

// ---------------- encoder staging (8 frags/chunk, per-wave private ring) ----------------
__device__ __forceinline__ void enc_stage(int c, int wv, int lane,
                                          const char* __restrict__ epb, char* __restrict__ ebuf)
{
    char* slot = ebuf + (c%3)*8192;
    if (c < 8){
        #pragma unroll
        for (int ktl=0;ktl<2;ktl++)
        #pragma unroll
        for (int nt=0;nt<2;nt++)
        #pragma unroll
        for (int hl=0;hl<2;hl++){
            int f = (wv*2+nt)*16 + (c*2+ktl);
            long fidx = hl ? (288+f) : f;
            stage16(epb + fidx*1024 + lane*16, slot + (ktl*4+nt*2+hl)*1024);
        }
    } else if (c < 10){
        #pragma unroll
        for (int ktl=0;ktl<2;ktl++)
        #pragma unroll
        for (int nt=0;nt<2;nt++)
        #pragma unroll
        for (int hl=0;hl<2;hl++){
            int f = 128 + (wv*2+nt)*4 + ((c-8)*2+ktl);
            long fidx = hl ? (288+f) : f;
            stage16(epb + fidx*1024 + lane*16, slot + (ktl*4+nt*2+hl)*1024);
        }
    } else {
        int nt = c - 10;
        #pragma unroll
        for (int kt=0;kt<4;kt++)
        #pragma unroll
        for (int hl=0;hl<2;hl++){
            int f = 160 + (wv*8+nt)*4 + kt;
            long fidx = hl ? (288+f) : f;
            stage16(epb + fidx*1024 + lane*16, slot + (kt*2+hl)*1024);
        }
    }
}

// ---------------- encoder phase (MFMA, DMA-staged weights) ----------------
__device__ void enc_phase(
    int e, const uint32_t* __restrict__ hsrc, uint32_t* __restrict__ htil,
    const char* __restrict__ epb, char* __restrict__ ebuf,
    const float bias1[2], const float bias2[2], const float bias3[8],
    float* __restrict__ t1, float* __restrict__ t2)
{
    const int tid = threadIdx.x;
    const int lane = tid & 63, wv = tid >> 6;
    const int c16 = lane & 15, kq = lane >> 4;
    const int r0 = e * 16;

    uint32_t hv[32];
    #pragma unroll
    for (int nt=0;nt<8;nt++)
      #pragma unroll
      for (int i=0;i<4;i++)
        hv[nt*4+i] = cld_u32(hsrc + (long)(r0+kq*4+i)*HH + wv*128 + nt*16 + c16);
    VMFENCE();

    const uint64_t* hp = (const uint64_t*)(hsrc + (long)(r0 + c16)*HH) + kq*4;
    uint64_t dA[32];
    #pragma unroll
    for (int kt=0;kt<8;kt++)
      #pragma unroll
      for (int i=0;i<4;i++)
        dA[kt*4+i] = cld_u64(hp + kt*16 + i);
    VMFENCE();

    enc_stage(0, wv, lane, epb, ebuf);
    VMFENCE();
    enc_stage(1, wv, lane, epb, ebuf);
    VMFENCE();
    WAITVM(16);
    s16x8 ah1[8], al1[8], ah2[8], al2[8];
    #pragma unroll
    for (int kt=0;kt<8;kt++) mk_frag(&dA[kt*4], &ah1[kt], &al1[kt]);
    #pragma unroll
    for (int kt=0;kt<8;kt++)
      #pragma unroll
      for (int i=0;i<4;i++)
        dA[kt*4+i] = cld_u64(hp + (kt+8)*16 + i);
    VMFENCE();

    f32x4 p1[2] = {{0,0,0,0},{0,0,0,0}};
    f32x4 p2[2] = {{0,0,0,0},{0,0,0,0}};
    #pragma unroll
    for (int c=0;c<8;c++){
        if (c < 2) { WAITVM(40); } else { WAITVM(8); }
        const s16x8* sb = (const s16x8*)(ebuf + (c%3)*8192);
        #pragma unroll
        for (int ktl=0;ktl<2;ktl++){
            const int kt = c*2 + ktl;
            s16x8 ah = (kt<8) ? ah1[kt&7] : ah2[kt&7];
            s16x8 al = (kt<8) ? al1[kt&7] : al2[kt&7];
            #pragma unroll
            for (int nt=0;nt<2;nt++){
                s16x8 bh = sb[(ktl*4+nt*2+0)*64 + lane];
                s16x8 bl = sb[(ktl*4+nt*2+1)*64 + lane];
                p1[nt] = MFMA(ah, bh, p1[nt]);
                p2[nt] = MFMA(al, bh, p2[nt]);
                p2[nt] = MFMA(ah, bl, p2[nt]);
            }
        }
        enc_stage(c+2, wv, lane, epb, ebuf);
        VMFENCE();
        if (c == 3){
            #pragma unroll
            for (int kt=0;kt<8;kt++) mk_frag(&dA[kt*4], &ah2[kt], &al2[kt]);
        }
    }
    #pragma unroll
    for (int nt=0;nt<2;nt++){
        f32x4 cc = p1[nt] + p2[nt];
        const int n = wv*32 + nt*16 + c16;
        #pragma unroll
        for (int i=0;i<4;i++) t1[(kq*4+i)*132 + n] = leakyf(cc[i] + bias1[nt]);
    }
    wgbar_lgkm();
    s16x8 a2h[4], a2l[4];
    #pragma unroll
    for (int kt=0;kt<4;kt++) pack8(t1 + c16*132 + kt*32 + kq*8, &a2h[kt], &a2l[kt]);
    f32x4 q1[2] = {{0,0,0,0},{0,0,0,0}};
    f32x4 q2[2] = {{0,0,0,0},{0,0,0,0}};
    #pragma unroll
    for (int c=8;c<10;c++){
        WAITVM(8);
        const s16x8* sb = (const s16x8*)(ebuf + (c%3)*8192);
        #pragma unroll
        for (int ktl=0;ktl<2;ktl++){
            const int kt = (c-8)*2 + ktl;
            #pragma unroll
            for (int nt=0;nt<2;nt++){
                s16x8 bh = sb[(ktl*4+nt*2+0)*64 + lane];
                s16x8 bl = sb[(ktl*4+nt*2+1)*64 + lane];
                q1[nt] = MFMA(a2h[kt], bh, q1[nt]);
                q2[nt] = MFMA(a2l[kt], bh, q2[nt]);
                q2[nt] = MFMA(a2h[kt], bl, q2[nt]);
            }
        }
        enc_stage(c+2, wv, lane, epb, ebuf);
        VMFENCE();
    }
    #pragma unroll
    for (int nt=0;nt<2;nt++){
        f32x4 cc = q1[nt] + q2[nt];
        const int n = wv*32 + nt*16 + c16;
        #pragma unroll
        for (int i=0;i<4;i++) t2[(kq*4+i)*132 + n] = leakyf(cc[i] + bias2[nt]);
    }
    wgbar_lgkm();
    s16x8 a3h[4], a3l[4];
    #pragma unroll
    for (int kt=0;kt<4;kt++) pack8(t2 + c16*132 + kt*32 + kq*8, &a3h[kt], &a3l[kt]);
    float av[8][4];
    #pragma unroll
    for (int c=10;c<18;c++){
        if (c < 17) { WAITVM(8); } else { WAITVM(0); }
        const int nt = c - 10;
        const s16x8* sb = (const s16x8*)(ebuf + (c%3)*8192);
        f32x4 s1 = {0,0,0,0}, s2 = {0,0,0,0};
        #pragma unroll
        for (int kt=0;kt<4;kt++){
            s16x8 bh = sb[(kt*2+0)*64 + lane];
            s16x8 bl = sb[(kt*2+1)*64 + lane];
            s1 = MFMA(a3h[kt], bh, s1);
            s2 = MFMA(a3l[kt], bh, s2);
            s2 = MFMA(a3h[kt], bl, s2);
        }
        f32x4 cc = s1 + s2;
        #pragma unroll
        for (int i=0;i<4;i++) av[nt][i] = alphaf(cc[i] + bias3[nt]);
        if (c + 2 < 18){
            enc_stage(c+2, wv, lane, epb, ebuf);
            VMFENCE();
        }
    }
    #pragma unroll
    for (int nt=0;nt<8;nt++)
      #pragma unroll
      for (int i=0;i<4;i++){
        const int row = r0 + kq*4 + i;
        const int n = wv*128 + nt*16 + c16;
        cst_u32(htil + (long)row*HH + n, packsplit(unpackf(hv[nt*4+i]) * av[nt][i]));
      }
}

// ---------------- persistent kernel ----------------
__global__ __launch_bounds__(256, 1) void persistent_kernel(
    const uint32_t* __restrict__ xp,
    uint32_t* __restrict__ hpack,
    const ushort* __restrict__ wpack,
    const ushort* __restrict__ epack,
    const float* __restrict__ c0in,
    const float* __restrict__ bih0, const float* __restrict__ bhh0,
    const float* __restrict__ bih1, const float* __restrict__ bhh1,
    const float* __restrict__ ehb1, const float* __restrict__ ehb2,
    const float* __restrict__ ehb3,
    float* __restrict__ out, int* __restrict__ bar)
{
    extern __shared__ char smem_raw[];
    const int wg = blockIdx.x, tid = threadIdx.x;
    uint32_t* h0p = hpack;
    uint32_t* h1p = hpack + 32768;
    uint32_t* ht0 = hpack + 65536;
    uint32_t* ht1 = hpack + 98304;

    if (wg >= NGATE){
        // -------- encoder wg (DMA-staged MFMA) --------
        char* ebuf = smem_raw + (tid>>6)*24576;       // per-wave 3x8KB ring
        float* t1 = (float*)(smem_raw + 98304);       // [16][132]
        float* t2 = t1 + 16*132;
        const int e = wg - NGATE;                     // 0..3
        const char* epb = (const char*)epack;
        const int lane = tid & 63, wv = tid >> 6, c16 = lane & 15;
        float bias1[2], bias2[2], bias3[8];
        #pragma unroll
        for (int nt = 0; nt < 2; nt++){
            bias1[nt] = ehb1[wv*32 + nt*16 + c16];
            bias2[nt] = ehb2[wv*32 + nt*16 + c16];
        }
        #pragma unroll
        for (int nt = 0; nt < 8; nt++)
            bias3[nt] = ehb3[wv*128 + nt*16 + c16];
        WAITVM(0);
        __syncthreads();
        for (int t = 0; t < TT; t++){
            enc_phase(e, h1p, ht1, epb, ebuf, bias1, bias2, bias3, t1, t2);
            gbar(bar, 2*t+1);
            enc_phase(e, h0p, ht0, epb, ebuf, bias1, bias2, bias3, t1, t2);
            gbar(bar, 2*t+2);
        }
        return;
    }
    // -------- gate wg: 32 gate-columns --------
    s16x8* whl = (s16x8*)smem_raw;                   // 7168 frags = 114688 B
    char*  wbuf = smem_raw + 114688;                 // 3x4KB ring (union glds)
    const int g = wg;
    const s16x8* wp = (const s16x8*)wpack;
    for (int i = tid; i < 7168; i += 256){
        int ng = (i >= 3584) ? 1 : 0;
        int r  = i - ng*3584;
        whl[i] = wp[(long)(2*g+ng)*7168 + r];
    }
    const s16x8* wlo0 = wp + (long)(2*g  )*7168 + 3584;
    const s16x8* wlo1 = wp + (long)(2*g+1)*7168 + 3584;

    const int jloc = tid & 7, bb2 = tid >> 3;
    const int jcol = g*8 + jloc;
    float bsum0[4], bsum1[4];
    #pragma unroll
    for (int q = 0; q < 4; q++){
        int n = q*512 + jcol;
        bsum0[q] = bih0[n] + bhh0[n];
        bsum1[q] = bih1[n] + bhh1[n];
    }
    float c0reg[2], c1reg[2], h0reg[2] = {0.f,0.f}, h1reg[2] = {0.f,0.f};
    #pragma unroll
    for (int half = 0; half < 2; half++){
        int b = bb2 + half*32;
        c0reg[half] = c0in[b*HH + jcol];
        c1reg[half] = c0in[32768 + b*HH + jcol];
    }
    WAITVM(0);
    __syncthreads();

    for (int t = 0; t < TT; t++){
        gate_phase<0>(t, g, tid, whl, wbuf, wlo0, wlo1,
                      xp, h0p, ht0, bsum0, h0p, c0reg, h0reg, nullptr);
        gbar(bar, 2*t+1);
        gate_phase<1>(t, g, tid, whl, wbuf, wlo0, wlo1,
                      xp, h0p, ht1, bsum1, h1p, c1reg, h1reg, out);
        gbar(bar, 2*t+2);
    }
    const long base = (long)BB*TT*HH;
    #pragma unroll
    for (int half = 0; half < 2; half++){
        int b = bb2 + half*32;
        out[base +                  b*HH + jcol] = h0reg[half];
        out[base + 32768          + b*HH + jcol] = h1reg[half];
        out[base + 65536          + b*HH + jcol] = c0reg[half];
        out[base + 65536 + 32768  + b*HH + jcol] = c1reg[half];
    }
}

// ---------------- launch ----------------
extern "C" void kernel_launch(void* const* d_in, const int* in_sizes, int n_in,
                              void* d_out, int out_size, void* d_ws, size_t ws_size,
                              hipStream_t stream)
{
    const float* input = (const float*)d_in[0];
    const float* h0in  = (const float*)d_in[1];
    const float* c0in  = (const float*)d_in[2];
    const float* Wih0  = (const float*)d_in[3];
    const float* Whh0  = (const float*)d_in[4];
    const float* bih0  = (const float*)d_in[5];
    const float* bhh0  = (const float*)d_in[6];
    const float* Wih1  = (const float*)d_in[7];
    const float* Whh1  = (const float*)d_in[8];
    const float* bih1  = (const float*)d_in[9];
    const float* bhh1  = (const float*)d_in[10];
    const float* eyw1  = (const float*)d_in[11];
    const float* eyb1  = (const float*)d_in[12];
    const float* eyw2  = (const float*)d_in[13];
    const float* eyb2  = (const float*)d_in[14];
    const float* eyw3  = (const float*)d_in[15];
    const float* eyb3  = (const float*)d_in[16];
    const float* ehw1  = (const float*)d_in[17];
    const float* ehb1  = (const float*)d_in[18];
    const float* ehw2  = (const float*)d_in[19];
    const float* ehb2  = (const float*)d_in[20];
    const float* ehw3  = (const float*)d_in[21];
    const float* ehb3  = (const float*)d_in[22];

    float* out = (float*)d_out;
    float* ws  = (float*)d_ws;

    // ws layout (4B units)
    uint32_t* xprime = (uint32_t*)ws;                  // [T][B][I] packed
    uint32_t* hpack  = (uint32_t*)(ws + 33554432);     // h0,h1,ht0,ht1
    int*      bar    = (int*)(ws + 33685504);          // 8 arrival lines + release
    ushort*   wpack  = (ushort*)(ws + 33751104);       // 14,680,064 B
    ushort*   epack  = (ushort*)(ws + 37421120);       // 589,824 B

    hipFuncSetAttribute((const void*)persistent_kernel,
                        hipFuncAttributeMaxDynamicSharedMemorySize, 131072);

    init_state_kernel<<<256, 256, 0, stream>>>(h0in, hpack, bar);
    prep_pack_kernel<<<128*56, 64, 0, stream>>>(Wih0, Whh0, Wih1, Whh1, wpack);
    enc_pack_kernel<<<288, 64, 0, stream>>>(ehw1, ehw2, ehw3, epack);
    ency_kernel<<<4096, 256, 0, stream>>>(input, xprime,
                                          eyw1, eyb1, eyw2, eyb2, eyw3, eyb3);
    enc_only_kernel<<<16, 256, 0, stream>>>(hpack, hpack + 65536,
                                            ehw1, ehb1, ehw2, ehb2, ehw3, ehb3);
    persistent_kernel<<<NWG, 256, 126976, stream>>>(
        xprime, hpack, wpack, epack, c0in,
        bih0, bhh0, bih1, bhh1,
        ehb1, ehb2, ehb3,
        out, bar);
}

// Round 9
// 85400.513 us; speedup vs baseline: 1.3886x; 1.0994x over previous
//
#include <hip/hip_runtime.h>
#include <math.h>
#include <stdint.h>

#define TT 2048
#define BB 64
#define II 256
#define HH 512
#define EHD 128
#define NGATE 64
#define NWG 68

typedef __attribute__((ext_vector_type(8))) short s16x8;
typedef __attribute__((ext_vector_type(4))) float f32x4;
typedef __attribute__((ext_vector_type(4))) uint32_t u32x4;

#define WAITVM(N) asm volatile("s_waitcnt vmcnt(" #N ")" ::: "memory")
#define VMFENCE() do { asm volatile("" ::: "memory"); __builtin_amdgcn_sched_barrier(0); } while(0)
#define SCHEDFENCE() __builtin_amdgcn_sched_barrier(0)

// ---------------- scalar helpers ----------------
__device__ __forceinline__ float dot4(const float4 a, const float4 b){
    return a.x*b.x + a.y*b.y + a.z*b.z + a.w*b.w;
}
__device__ __forceinline__ float sigm(float x){ return 1.0f/(1.0f+expf(-x)); }
__device__ __forceinline__ float leakyf(float x){ return x > 0.0f ? x : 0.01f*x; }
__device__ __forceinline__ float alphaf(float x){
    float p = 1.0f/(1.0f+expf(-x));
    return p/(1.0f-p);
}
__device__ __forceinline__ f32x4 MFMA(s16x8 a, s16x8 b, f32x4 c){
    return __builtin_amdgcn_mfma_f32_16x16x32_bf16(a, b, c, 0, 0, 0);
}

// ---------------- coherent (cross-XCD) access ----------------
__device__ __forceinline__ uint32_t cld_u32(const uint32_t* p){
    return __hip_atomic_load(p, __ATOMIC_RELAXED, __HIP_MEMORY_SCOPE_AGENT);
}
__device__ __forceinline__ void cst_u32(uint32_t* p, uint32_t v){
    __hip_atomic_store(p, v, __ATOMIC_RELAXED, __HIP_MEMORY_SCOPE_AGENT);
}
// wide coherent load: 2x global_load_dwordx4 with sc0 sc1 (same policy bits
// the compiler emits for agent-scope atomic loads) -> 32B/lane in 2 VM ops
__device__ __forceinline__ void cld2x4(const void* p, u32x4& a, u32x4& b){
    asm volatile("global_load_dwordx4 %0, %2, off sc0 sc1\n\t"
                 "global_load_dwordx4 %1, %2, off offset:16 sc0 sc1"
                 : "=&v"(a), "=&v"(b) : "v"(p) : "memory");
}
// wide cached load (read-only data): same shape, no policy bits
__device__ __forceinline__ void ld2x4(const void* p, u32x4& a, u32x4& b){
    asm volatile("global_load_dwordx4 %0, %2, off\n\t"
                 "global_load_dwordx4 %1, %2, off offset:16"
                 : "=&v"(a), "=&v"(b) : "v"(p) : "memory");
}

// packed bf16 hi/lo pair
__device__ __forceinline__ uint32_t packsplit(float v){
    uint32_t u  = __float_as_uint(v);
    uint32_t hi = u & 0xFFFF0000u;
    float    lo = v - __uint_as_float(hi);
    return hi | (__float_as_uint(lo) >> 16);
}
__device__ __forceinline__ float unpackf(uint32_t w){
    return __uint_as_float(w & 0xFFFF0000u) + __uint_as_float(w << 16);
}

// ---------------- async global->LDS ----------------
__device__ __forceinline__ void stage16(const void* g, void* l){
    __builtin_amdgcn_global_load_lds(
        (const __attribute__((address_space(1))) void*)g,
        (__attribute__((address_space(3))) void*)l, 16, 0, 0);
}

// ---------------- release-flag barrier (R8, proven) ----------------
__device__ __forceinline__ int bar_sum(const int* bar){
    int s = 0;
    #pragma unroll
    for (int i = 0; i < 8; i++)
        s += (int)cld_u32((const uint32_t*)(bar + i*32));
    return s;
}
__device__ __forceinline__ void gbar(int* bar, int epoch){
    asm volatile("s_waitcnt vmcnt(0)" ::: "memory");
    __syncthreads();
    if (threadIdx.x == 0){
        __hip_atomic_fetch_add(bar + (blockIdx.x & 7)*32, 1,
                               __ATOMIC_RELAXED, __HIP_MEMORY_SCOPE_AGENT);
        if (blockIdx.x == 0){
            const int target = NWG * epoch;
            while (bar_sum(bar) < target)
                __builtin_amdgcn_s_sleep(1);
            cst_u32((uint32_t*)(bar + 8*32), (uint32_t)epoch);
        } else {
            while ((int)cld_u32((const uint32_t*)(bar + 8*32)) < epoch)
                __builtin_amdgcn_s_sleep(2);
        }
    }
    __syncthreads();
}

// workgroup barrier flavors
__device__ __forceinline__ void wgbar(){ __builtin_amdgcn_s_barrier(); }
__device__ __forceinline__ void wgbar_lgkm(){
    asm volatile("s_waitcnt lgkmcnt(0)" ::: "memory");
    __builtin_amdgcn_s_barrier();
}

// ---------------- fragment builders ----------------
// from two dwordx4 results: a = packed u32 at k0..k3, b = k4..k7
__device__ __forceinline__ void mk_frag2(u32x4 a, u32x4 b, s16x8* hi, s16x8* lo){
    union { u32x4 u; s16x8 s; } H, L;
    H.u[0] = __builtin_amdgcn_perm(a[1], a[0], 0x07060302u);
    H.u[1] = __builtin_amdgcn_perm(a[3], a[2], 0x07060302u);
    H.u[2] = __builtin_amdgcn_perm(b[1], b[0], 0x07060302u);
    H.u[3] = __builtin_amdgcn_perm(b[3], b[2], 0x07060302u);
    L.u[0] = __builtin_amdgcn_perm(a[1], a[0], 0x05040100u);
    L.u[1] = __builtin_amdgcn_perm(a[3], a[2], 0x05040100u);
    L.u[2] = __builtin_amdgcn_perm(b[1], b[0], 0x05040100u);
    L.u[3] = __builtin_amdgcn_perm(b[3], b[2], 0x05040100u);
    *hi = H.s; *lo = L.s;
}
__device__ __forceinline__ void pack8(const float* f, s16x8* hi, s16x8* lo){
    union { u32x4 u; s16x8 s; } H, L;
    #pragma unroll
    for (int i = 0; i < 4; i++){
        float a = f[2*i], b = f[2*i+1];
        uint32_t ua = __float_as_uint(a), ub = __float_as_uint(b);
        uint32_t ha = ua & 0xFFFF0000u, hb = ub & 0xFFFF0000u;
        H.u[i] = (ua >> 16) | hb;
        float la = a - __uint_as_float(ha), lb = b - __uint_as_float(hb);
        L.u[i] = (__float_as_uint(la) >> 16) | (__float_as_uint(lb) & 0xFFFF0000u);
    }
    *hi = H.s; *lo = L.s;
}

// ---------------- fp32 encoder block (PROLOGUE ONLY) ----------------
__device__ void enc_h_block(int e, const uint32_t* __restrict__ hsrc,
                            uint32_t* __restrict__ htil,
                            const float* __restrict__ w1, const float* __restrict__ b1,
                            const float* __restrict__ w2, const float* __restrict__ b2,
                            const float* __restrict__ w3, const float* __restrict__ b3,
                            float* smem)
{
    float* hlds = smem;              // [4][516]
    float* t1   = smem + 4*516;      // [4][132]
    float* t2   = t1 + 4*132;        // [4][132]
    const int tid = threadIdx.x;
    const int r0 = e * 4;
    #pragma unroll
    for (int i = 0; i < 8; i++){
        int el = tid + i*256;
        int rr = el >> 9, k = el & 511;
        hlds[rr*516 + k] = unpackf(cld_u32(hsrc + (r0+rr)*HH + k));
    }
    __syncthreads();
    const int cc = tid & 63;
    const int rr = (tid >> 6) & 3;
    for (int cb = 0; cb < 2; cb++){
        int c = cc + cb*64;
        const float* wr = w1 + c*HH;
        const float* xr = hlds + rr*516;
        float a0 = b1[c], a1 = 0.f;
        #pragma unroll 8
        for (int k = 0; k < HH; k += 8){
            a0 += dot4(*(const float4*)(xr+k),   *(const float4*)(wr+k));
            a1 += dot4(*(const float4*)(xr+k+4), *(const float4*)(wr+k+4));
        }
        t1[rr*132 + c] = leakyf(a0 + a1);
    }
    __syncthreads();
    for (int cb = 0; cb < 2; cb++){
        int c = cc + cb*64;
        const float* wr = w2 + c*EHD;
        const float* xr = t1 + rr*132;
        float a0 = b2[c], a1 = 0.f;
        #pragma unroll 4
        for (int k = 0; k < EHD; k += 8){
            a0 += dot4(*(const float4*)(xr+k),   *(const float4*)(wr+k));
            a1 += dot4(*(const float4*)(xr+k+4), *(const float4*)(wr+k+4));
        }
        t2[rr*132 + c] = leakyf(a0 + a1);
    }
    __syncthreads();
    for (int cb = 0; cb < 8; cb++){
        int c = cc + cb*64;
        const float* wr = w3 + c*EHD;
        const float* xr = t2 + rr*132;
        float a0 = b3[c], a1 = 0.f;
        #pragma unroll 4
        for (int k = 0; k < EHD; k += 8){
            a0 += dot4(*(const float4*)(xr+k),   *(const float4*)(wr+k));
            a1 += dot4(*(const float4*)(xr+k+4), *(const float4*)(wr+k+4));
        }
        float a = alphaf(a0 + a1);
        cst_u32(htil + (r0+rr)*HH + c, packsplit(hlds[rr*516 + c] * a));
    }
    __syncthreads();
}

__global__ __launch_bounds__(256) void enc_only_kernel(
    const uint32_t* __restrict__ hsrc, uint32_t* __restrict__ htil,
    const float* __restrict__ w1, const float* __restrict__ b1,
    const float* __restrict__ w2, const float* __restrict__ b2,
    const float* __restrict__ w3, const float* __restrict__ b3)
{
    __shared__ float smem[3120];
    enc_h_block(blockIdx.x, hsrc, htil, w1, b1, w2, b2, w3, b3, smem);
}

// ---------------- x' = input * alpha_y(input): packed, [T][B][I] ----------------
__global__ __launch_bounds__(256) void ency_kernel(
    const float* __restrict__ xin, uint32_t* __restrict__ xprime,
    const float* __restrict__ w1, const float* __restrict__ b1,
    const float* __restrict__ w2, const float* __restrict__ b2,
    const float* __restrict__ w3, const float* __restrict__ b3)
{
    __shared__ float t1[32*128];
    __shared__ float t2[32*128];
    const long m0 = (long)blockIdx.x * 32;
    const int tid = threadIdx.x;
    const int cc = tid & 63;
    const int rr = tid >> 6;
    for (int cb = 0; cb < 2; cb++){
        int c = cc + cb*64;
        const float* wr = w1 + c*II;
        for (int q = 0; q < 8; q++){
            int r = rr*8 + q;
            const float* xr = xin + (m0 + r)*II;
            float a0 = b1[c], a1 = 0.f;
            #pragma unroll 8
            for (int k = 0; k < II; k += 8){
                a0 += dot4(*(const float4*)(xr+k),   *(const float4*)(wr+k));
                a1 += dot4(*(const float4*)(xr+k+4), *(const float4*)(wr+k+4));
            }
            t1[r*128 + c] = leakyf(a0 + a1);
        }
    }
    __syncthreads();
    for (int cb = 0; cb < 2; cb++){
        int c = cc + cb*64;
        const float* wr = w2 + c*EHD;
        for (int q = 0; q < 8; q++){
            int r = rr*8 + q;
            const float* xr = t1 + r*128;
            float a0 = b2[c], a1 = 0.f;
            #pragma unroll 4
            for (int k = 0; k < EHD; k += 8){
                a0 += dot4(*(const float4*)(xr+k),   *(const float4*)(wr+k));
                a1 += dot4(*(const float4*)(xr+k+4), *(const float4*)(wr+k+4));
            }
            t2[r*128 + c] = leakyf(a0 + a1);
        }
    }
    __syncthreads();
    for (int cb = 0; cb < 4; cb++){
        int c = cc + cb*64;
        const float* wr = w3 + c*EHD;
        for (int q = 0; q < 8; q++){
            int r = rr*8 + q;
            const float* xr = t2 + r*128;
            float a0 = b3[c], a1 = 0.f;
            #pragma unroll 4
            for (int k = 0; k < EHD; k += 8){
                a0 += dot4(*(const float4*)(xr+k),   *(const float4*)(wr+k));
                a1 += dot4(*(const float4*)(xr+k+4), *(const float4*)(wr+k+4));
            }
            float a = alphaf(a0 + a1);
            long m = m0 + r;                       // m = b*TT + t
            long b = m >> 11, t = m & 2047;
            xprime[((long)t*BB + b)*II + c] = packsplit(xin[m*II + c] * a);
        }
    }
}

// ---------------- gate weight packing ----------------
__global__ __launch_bounds__(64) void prep_pack_kernel(
    const float* __restrict__ Wih0, const float* __restrict__ Whh0,
    const float* __restrict__ Wih1, const float* __restrict__ Whh1,
    ushort* __restrict__ wpack)
{
    const int b = blockIdx.x;          // 128*56
    const int lane = threadIdx.x;
    const int g4 = b / 56, kts = b % 56;
    const int layer = (kts >= 24) ? 1 : 0;
    const int kt = layer ? (kts - 24) : kts;
    const int c = lane & 15;
    const int gate = c >> 2, uu = c & 3;
    const int n = gate*512 + g4*4 + uu;
    const int k = kt*32 + (lane >> 4)*8;
    const float* src;
    if (!layer){
        if (k < 256) src = Wih0 + (long)n*II + k;
        else         src = Whh0 + (long)n*HH + (k - 256);
    } else {
        if (k < 512) src = Wih1 + (long)n*HH + k;
        else         src = Whh1 + (long)n*HH + (k - 512);
    }
    ushort hi[8], lo[8];
    #pragma unroll
    for (int j = 0; j < 8; j++){
        float v = src[j];
        uint32_t u = __float_as_uint(v);
        hi[j] = (ushort)(u >> 16);
        float hf = __uint_as_float(u & 0xFFFF0000u);
        lo[j] = (ushort)(__float_as_uint(v - hf) >> 16);
    }
    long bhi = ((long)g4*7168 + kts*64 + lane) * 8;
    long blo = bhi + (long)3584*8;
    #pragma unroll
    for (int j = 0; j < 8; j++){ wpack[bhi + j] = hi[j]; wpack[blo + j] = lo[j]; }
}

// ---------------- encoder weight packing ----------------
__global__ __launch_bounds__(64) void enc_pack_kernel(
    const float* __restrict__ w1, const float* __restrict__ w2,
    const float* __restrict__ w3, ushort* __restrict__ epack)
{
    const int f = blockIdx.x;      // 0..287
    const int lane = threadIdx.x;
    const int c = lane & 15, kq = lane >> 4;
    const float* src;
    if (f < 128){
        int nt = f >> 4, kt = f & 15;
        src = w1 + (long)(nt*16 + c)*HH + kt*32 + kq*8;
    } else if (f < 160){
        int q = f - 128; int nt = q >> 2, kt = q & 3;
        src = w2 + (long)(nt*16 + c)*EHD + kt*32 + kq*8;
    } else {
        int q = f - 160; int nt = q >> 2, kt = q & 3;
        src = w3 + (long)(nt*16 + c)*EHD + kt*32 + kq*8;
    }
    long off = ((long)f*64 + lane)*8;
    #pragma unroll
    for (int j = 0; j < 8; j++){
        float v = src[j];
        uint32_t u = __float_as_uint(v);
        epack[off + j] = (ushort)(u >> 16);
        float hf = __uint_as_float(u & 0xFFFF0000u);
        epack[off + 147456 + j] = (ushort)(__float_as_uint(v - hf) >> 16);
    }
}

// ---------------- init ----------------
__global__ __launch_bounds__(256) void init_state_kernel(
    const float* __restrict__ h0, uint32_t* __restrict__ hpack, int* __restrict__ bar)
{
    int i = blockIdx.x*256 + threadIdx.x;
    hpack[i] = packsplit(h0[i]);
    if (i < 320) bar[i] = 0;
}

// ---------------- gate helpers ----------------
struct Accs { f32x4 a1, a2, b1, b2; };

// one 4-kt chunk of A: 8 dwordx4 ops (coherent for h/htil, cached for x')
template<int PHASE>
__device__ __forceinline__ void gate_aload4(int c, int t, int brow, int kq,
    const uint32_t* __restrict__ xp, const uint32_t* __restrict__ h0p,
    const uint32_t* __restrict__ htilp, u32x4* d /*[8]*/)
{
    #pragma unroll
    for (int ktl = 0; ktl < 4; ktl++){
        const int kt = c*4 + ktl;
        if (PHASE == 0){
            if (kt < 8){
                const char* p = (const char*)(xp + ((long)t*BB + brow)*II) + kt*128 + kq*32;
                ld2x4(p, d[ktl*2], d[ktl*2+1]);
            } else {
                const char* p = (const char*)(htilp + (long)brow*HH) + (kt-8)*128 + kq*32;
                cld2x4(p, d[ktl*2], d[ktl*2+1]);
            }
        } else {
            const char* p;
            if (kt < 16) p = (const char*)(h0p + (long)brow*HH) + kt*128 + kq*32;
            else         p = (const char*)(htilp + (long)brow*HH) + (kt-16)*128 + kq*32;
            cld2x4(p, d[ktl*2], d[ktl*2+1]);
        }
    }
}

// stage one 4-kt chunk of lo-weights: wave wv stages ktl=wv, both n-groups (2 ops)
__device__ __forceinline__ void gate_stage4(int c, int wv, int lane, int KT0,
    const s16x8* __restrict__ wlo0, const s16x8* __restrict__ wlo1,
    char* __restrict__ wbuf)
{
    char* slot = wbuf + (c%3)*8192;
    const int ktg = KT0 + c*4 + wv;
    stage16((const char*)(wlo0 + (long)ktg*64) + lane*16, slot + (wv*2+0)*1024);
    stage16((const char*)(wlo1 + (long)ktg*64) + lane*16, slot + (wv*2+1)*1024);
}

// ---------------- gate phase: 4-kt chunks, wide coherent A, DMA lo-weights ----------------
template<int PHASE>
__device__ __forceinline__ void gate_phase(
    int t, int g, int tid,
    const s16x8* __restrict__ whl, char* __restrict__ wbuf,
    const s16x8* __restrict__ wlo0, const s16x8* __restrict__ wlo1,
    const uint32_t* __restrict__ xp,
    const uint32_t* __restrict__ h0p,
    const uint32_t* __restrict__ htilp,
    const float* bsum, uint32_t* __restrict__ hdst,
    float creg[2], float hreg[2], float* __restrict__ yout)
{
    const int lane = tid & 63;
    const int wv   = tid >> 6;
    const int brow = wv*16 + (lane & 15);
    const int kq   = lane >> 4;
    constexpr int NCH = PHASE ? 8 : 6;
    constexpr int KT0 = PHASE ? 24 : 0;

    Accs ac = {};
    u32x4 dA[2][8];

    // prologue: chunks 0,1 — per chunk [S(2), A(8)] = 10 VM ops, order pinned
    gate_stage4(0, wv, lane, KT0, wlo0, wlo1, wbuf);
    VMFENCE();
    gate_aload4<PHASE>(0, t, brow, kq, xp, h0p, htilp, dA[0]);
    VMFENCE();
    gate_stage4(1, wv, lane, KT0, wlo0, wlo1, wbuf);
    VMFENCE();
    gate_aload4<PHASE>(1, t, brow, kq, xp, h0p, htilp, dA[1]);
    VMFENCE();

    #pragma unroll
    for (int c = 0; c < NCH; c++){
        // entering iter c: chunks c, c+1 outstanding (20 ops).
        // WAITVM(10) retires chunk c entirely (slot + dA[c&1]).
        if (c < NCH-1) { WAITVM(10); } else { WAITVM(0); }
        wgbar();                                  // all waves' chunk-c staging arrived
        SCHEDFENCE();                             // rule #18: no hoist past the wait
        s16x8 ah[4], al[4];
        #pragma unroll
        for (int ktl = 0; ktl < 4; ktl++)
            mk_frag2(dA[c&1][ktl*2], dA[c&1][ktl*2+1], &ah[ktl], &al[ktl]);
        if (c + 2 < NCH){
            gate_stage4(c+2, wv, lane, KT0, wlo0, wlo1, wbuf);
            VMFENCE();
            gate_aload4<PHASE>(c+2, t, brow, kq, xp, h0p, htilp, dA[c&1]);
            VMFENCE();
        }
        const s16x8* sb = (const s16x8*)(wbuf + (c%3)*8192);
        #pragma unroll
        for (int ktl = 0; ktl < 4; ktl++){
            const int ktg = KT0 + c*4 + ktl;
            { s16x8 B1 = whl[ktg*64 + lane];
              s16x8 B2 = sb[(ktl*2+0)*64 + lane];
              ac.a1 = MFMA(ah[ktl], B1, ac.a1);
              ac.a2 = MFMA(al[ktl], B1, ac.a2);
              ac.a2 = MFMA(ah[ktl], B2, ac.a2); }
            { s16x8 B1 = whl[3584 + ktg*64 + lane];
              s16x8 B2 = sb[(ktl*2+1)*64 + lane];
              ac.b1 = MFMA(ah[ktl], B1, ac.b1);
              ac.b2 = MFMA(al[ktl], B1, ac.b2);
              ac.b2 = MFMA(ah[ktl], B2, ac.b2); }
        }
    }
    wgbar_lgkm();
    float* glds = (float*)wbuf;                  // union with staging ring (24KB)
    {
        f32x4 caf = ac.a1 + ac.a2;
        f32x4 cbf = ac.b1 + ac.b2;
        const int r0 = wv*16 + (lane>>4)*4;
        const int c16 = lane & 15;
        #pragma unroll
        for (int i = 0; i < 4; i++){
            glds[(r0+i)*33 + c16]      = caf[i];
            glds[(r0+i)*33 + 16 + c16] = cbf[i];
        }
    }
    wgbar_lgkm();
    {
        const int jloc = tid & 7, bb2 = tid >> 3;
        const int ng = jloc >> 2, uu = jloc & 3;
        const int jcol = g*8 + jloc;
        #pragma unroll
        for (int half = 0; half < 2; half++){
            int b = bb2 + half*32;
            float gi = glds[b*33 + ng*16 + 0  + uu] + bsum[0];
            float gf = glds[b*33 + ng*16 + 4  + uu] + bsum[1];
            float gg = glds[b*33 + ng*16 + 8  + uu] + bsum[2];
            float go = glds[b*33 + ng*16 + 12 + uu] + bsum[3];
            float cn = sigm(gf)*creg[half] + sigm(gi)*tanhf(gg);
            float hn = sigm(go)*tanhf(cn);
            creg[half] = cn; hreg[half] = hn;
            cst_u32(hdst + b*HH + jcol, packsplit(hn));
            if (yout) yout[((long)b*TT + t)*HH + jcol] = hn;
        }
    }
}

// ---------------- encoder staging (8 frags/chunk, per-wave private ring) ----------------
__device__ __forceinline__ void enc_stage(int c, int wv, int lane,
                                          const char* __restrict__ epb, char* __restrict__ ebuf)
{
    char* slot = ebuf + (c%3)*8192;
    if (c < 8){
        #pragma unroll
        for (int ktl=0;ktl<2;ktl++)
        #pragma unroll
        for (int nt=0;nt<2;nt++)
        #pragma unroll
        for (int hl=0;hl<2;hl++){
            int f = (wv*2+nt)*16 + (c*2+ktl);
            long fidx = hl ? (288+f) : f;
            stage16(epb + fidx*1024 + lane*16, slot + (ktl*4+nt*2+hl)*1024);
        }
    } else if (c < 10){
        #pragma unroll
        for (int ktl=0;ktl<2;ktl++)
        #pragma unroll
        for (int nt=0;nt<2;nt++)
        #pragma unroll
        for (int hl=0;hl<2;hl++){
            int f = 128 + (wv*2+nt)*4 + ((c-8)*2+ktl);
            long fidx = hl ? (288+f) : f;
            stage16(epb + fidx*1024 + lane*16, slot + (ktl*4+nt*2+hl)*1024);
        }
    } else {
        int nt = c - 10;
        #pragma unroll
        for (int kt=0;kt<4;kt++)
        #pragma unroll
        for (int hl=0;hl<2;hl++){
            int f = 160 + (wv*8+nt)*4 + kt;
            long fidx = hl ? (288+f) : f;
            stage16(epb + fidx*1024 + lane*16, slot + (kt*2+hl)*1024);
        }
    }
}

// ---------------- encoder phase (MFMA, DMA-staged weights, wide coherent A) ----------------
__device__ void enc_phase(
    int e, const uint32_t* __restrict__ hsrc, uint32_t* __restrict__ htil,
    const char* __restrict__ epb, char* __restrict__ ebuf,
    const float bias1[2], const float bias2[2], const float bias3[8],
    float* __restrict__ t1, float* __restrict__ t2)
{
    const int tid = threadIdx.x;
    const int lane = tid & 63, wv = tid >> 6;
    const int c16 = lane & 15, kq = lane >> 4;
    const int r0 = e * 16;

    uint32_t hv[32];
    #pragma unroll
    for (int nt=0;nt<8;nt++)
      #pragma unroll
      for (int i=0;i<4;i++)
        hv[nt*4+i] = cld_u32(hsrc + (long)(r0+kq*4+i)*HH + wv*128 + nt*16 + c16);
    VMFENCE();

    // A first half (kt 0..7): 16 coherent dwordx4 ops
    const char* hp = (const char*)(hsrc + (long)(r0 + c16)*HH) + kq*32;
    u32x4 dq[16];
    #pragma unroll
    for (int kt=0;kt<8;kt++)
        cld2x4(hp + kt*128, dq[kt*2], dq[kt*2+1]);
    VMFENCE();

    enc_stage(0, wv, lane, epb, ebuf);
    VMFENCE();
    enc_stage(1, wv, lane, epb, ebuf);
    VMFENCE();
    WAITVM(16);                     // queue [hv(32),A0(16),S0(8),S1(8)] -> leaves S0,S1
    SCHEDFENCE();
    s16x8 ah1[8], al1[8], ah2[8], al2[8];
    #pragma unroll
    for (int kt=0;kt<8;kt++) mk_frag2(dq[kt*2], dq[kt*2+1], &ah1[kt], &al1[kt]);
    // A second half (kt 8..15)
    #pragma unroll
    for (int kt=0;kt<8;kt++)
        cld2x4(hp + 1024 + kt*128, dq[kt*2], dq[kt*2+1]);
    VMFENCE();

    f32x4 p1[2] = {{0,0,0,0},{0,0,0,0}};
    f32x4 p2[2] = {{0,0,0,0},{0,0,0,0}};
    #pragma unroll
    for (int c=0;c<8;c++){
        if (c < 2) { WAITVM(24); } else { WAITVM(8); }   // c<2: leave S_{c+1}+A1
        SCHEDFENCE();
        const s16x8* sb = (const s16x8*)(ebuf + (c%3)*8192);
        #pragma unroll
        for (int ktl=0;ktl<2;ktl++){
            const int kt = c*2 + ktl;
            s16x8 ah = (kt<8) ? ah1[kt&7] : ah2[kt&7];
            s16x8 al = (kt<8) ? al1[kt&7] : al2[kt&7];
            #pragma unroll
            for (int nt=0;nt<2;nt++){
                s16x8 bh = sb[(ktl*4+nt*2+0)*64 + lane];
                s16x8 bl = sb[(ktl*4+nt*2+1)*64 + lane];
                p1[nt] = MFMA(ah, bh, p1[nt]);
                p2[nt] = MFMA(al, bh, p2[nt]);
                p2[nt] = MFMA(ah, bl, p2[nt]);
            }
        }
        enc_stage(c+2, wv, lane, epb, ebuf);
        VMFENCE();
        if (c == 3){   // A1 drained by c=2's WAITVM(8)
            #pragma unroll
            for (int kt=0;kt<8;kt++) mk_frag2(dq[kt*2], dq[kt*2+1], &ah2[kt], &al2[kt]);
        }
    }
    #pragma unroll
    for (int nt=0;nt<2;nt++){
        f32x4 cc = p1[nt] + p2[nt];
        const int n = wv*32 + nt*16 + c16;
        #pragma unroll
        for (int i=0;i<4;i++) t1[(kq*4+i)*132 + n] = leakyf(cc[i] + bias1[nt]);
    }
    wgbar_lgkm();
    s16x8 a2h[4], a2l[4];
    #pragma unroll
    for (int kt=0;kt<4;kt++) pack8(t1 + c16*132 + kt*32 + kq*8, &a2h[kt], &a2l[kt]);
    f32x4 q1[2] = {{0,0,0,0},{0,0,0,0}};
    f32x4 q2[2] = {{0,0,0,0},{0,0,0,0}};
    #pragma unroll
    for (int c=8;c<10;c++){
        WAITVM(8);
        const s16x8* sb = (const s16x8*)(ebuf + (c%3)*8192);
        #pragma unroll
        for (int ktl=0;ktl<2;ktl++){
            const int kt = (c-8)*2 + ktl;
            #pragma unroll
            for (int nt=0;nt<2;nt++){
                s16x8 bh = sb[(ktl*4+nt*2+0)*64 + lane];
                s16x8 bl = sb[(ktl*4+nt*2+1)*64 + lane];
                q1[nt] = MFMA(a2h[kt], bh, q1[nt]);
                q2[nt] = MFMA(a2l[kt], bh, q2[nt]);
                q2[nt] = MFMA(a2h[kt], bl, q2[nt]);
            }
        }
        enc_stage(c+2, wv, lane, epb, ebuf);
        VMFENCE();
    }
    #pragma unroll
    for (int nt=0;nt<2;nt++){
        f32x4 cc = q1[nt] + q2[nt];
        const int n = wv*32 + nt*16 + c16;
        #pragma unroll
        for (int i=0;i<4;i++) t2[(kq*4+i)*132 + n] = leakyf(cc[i] + bias2[nt]);
    }
    wgbar_lgkm();
    s16x8 a3h[4], a3l[4];
    #pragma unroll
    for (int kt=0;kt<4;kt++) pack8(t2 + c16*132 + kt*32 + kq*8, &a3h[kt], &a3l[kt]);
    float av[8][4];
    #pragma unroll
    for (int c=10;c<18;c++){
        if (c < 17) { WAITVM(8); } else { WAITVM(0); }
        const int nt = c - 10;
        const s16x8* sb = (const s16x8*)(ebuf + (c%3)*8192);
        f32x4 s1 = {0,0,0,0}, s2 = {0,0,0,0};
        #pragma unroll
        for (int kt=0;kt<4;kt++){
            s16x8 bh = sb[(kt*2+0)*64 + lane];
            s16x8 bl = sb[(kt*2+1)*64 + lane];
            s1 = MFMA(a3h[kt], bh, s1);
            s2 = MFMA(a3l[kt], bh, s2);
            s2 = MFMA(a3h[kt], bl, s2);
        }
        f32x4 cc = s1 + s2;
        #pragma unroll
        for (int i=0;i<4;i++) av[nt][i] = alphaf(cc[i] + bias3[nt]);
        if (c + 2 < 18){
            enc_stage(c+2, wv, lane, epb, ebuf);
            VMFENCE();
        }
    }
    #pragma unroll
    for (int nt=0;nt<8;nt++)
      #pragma unroll
      for (int i=0;i<4;i++){
        const int row = r0 + kq*4 + i;
        const int n = wv*128 + nt*16 + c16;
        cst_u32(htil + (long)row*HH + n, packsplit(unpackf(hv[nt*4+i]) * av[nt][i]));
      }
}

// ---------------- persistent kernel ----------------
__global__ __launch_bounds__(256, 1) void persistent_kernel(
    const uint32_t* __restrict__ xp,
    uint32_t* __restrict__ hpack,
    const ushort* __restrict__ wpack,
    const ushort* __restrict__ epack,
    const float* __restrict__ c0in,
    const float* __restrict__ bih0, const float* __restrict__ bhh0,
    const float* __restrict__ bih1, const float* __restrict__ bhh1,
    const float* __restrict__ ehb1, const float* __restrict__ ehb2,
    const float* __restrict__ ehb3,
    float* __restrict__ out, int* __restrict__ bar)
{
    extern __shared__ char smem_raw[];
    const int wg = blockIdx.x, tid = threadIdx.x;
    uint32_t* h0p = hpack;
    uint32_t* h1p = hpack + 32768;
    uint32_t* ht0 = hpack + 65536;
    uint32_t* ht1 = hpack + 98304;

    if (wg >= NGATE){
        // -------- encoder wg (DMA-staged MFMA) --------
        char* ebuf = smem_raw + (tid>>6)*24576;       // per-wave 3x8KB ring
        float* t1 = (float*)(smem_raw + 98304);       // [16][132]
        float* t2 = t1 + 16*132;
        const int e = wg - NGATE;                     // 0..3
        const char* epb = (const char*)epack;
        const int lane = tid & 63, wv = tid >> 6, c16 = lane & 15;
        float bias1[2], bias2[2], bias3[8];
        #pragma unroll
        for (int nt = 0; nt < 2; nt++){
            bias1[nt] = ehb1[wv*32 + nt*16 + c16];
            bias2[nt] = ehb2[wv*32 + nt*16 + c16];
        }
        #pragma unroll
        for (int nt = 0; nt < 8; nt++)
            bias3[nt] = ehb3[wv*128 + nt*16 + c16];
        WAITVM(0);
        __syncthreads();
        for (int t = 0; t < TT; t++){
            enc_phase(e, h1p, ht1, epb, ebuf, bias1, bias2, bias3, t1, t2);
            gbar(bar, 2*t+1);
            enc_phase(e, h0p, ht0, epb, ebuf, bias1, bias2, bias3, t1, t2);
            gbar(bar, 2*t+2);
        }
        return;
    }
    // -------- gate wg: 32 gate-columns --------
    s16x8* whl = (s16x8*)smem_raw;                   // 7168 frags = 114688 B
    char*  wbuf = smem_raw + 114688;                 // 3x8KB ring (union glds)
    const int g = wg;
    const s16x8* wp = (const s16x8*)wpack;
    for (int i = tid; i < 7168; i += 256){
        int ng = (i >= 3584) ? 1 : 0;
        int r  = i - ng*3584;
        whl[i] = wp[(long)(2*g+ng)*7168 + r];
    }
    const s16x8* wlo0 = wp + (long)(2*g  )*7168 + 3584;
    const s16x8* wlo1 = wp + (long)(2*g+1)*7168 + 3584;

    const int jloc = tid & 7, bb2 = tid >> 3;
    const int jcol = g*8 + jloc;
    float bsum0[4], bsum1[4];
    #pragma unroll
    for (int q = 0; q < 4; q++){
        int n = q*512 + jcol;
        bsum0[q] = bih0[n] + bhh0[n];
        bsum1[q] = bih1[n] + bhh1[n];
    }
    float c0reg[2], c1reg[2], h0reg[2] = {0.f,0.f}, h1reg[2] = {0.f,0.f};
    #pragma unroll
    for (int half = 0; half < 2; half++){
        int b = bb2 + half*32;
        c0reg[half] = c0in[b*HH + jcol];
        c1reg[half] = c0in[32768 + b*HH + jcol];
    }
    WAITVM(0);
    __syncthreads();

    for (int t = 0; t < TT; t++){
        gate_phase<0>(t, g, tid, whl, wbuf, wlo0, wlo1,
                      xp, h0p, ht0, bsum0, h0p, c0reg, h0reg, nullptr);
        gbar(bar, 2*t+1);
        gate_phase<1>(t, g, tid, whl, wbuf, wlo0, wlo1,
                      xp, h0p, ht1, bsum1, h1p, c1reg, h1reg, out);
        gbar(bar, 2*t+2);
    }
    const long base = (long)BB*TT*HH;
    #pragma unroll
    for (int half = 0; half < 2; half++){
        int b = bb2 + half*32;
        out[base +                  b*HH + jcol] = h0reg[half];
        out[base + 32768          + b*HH + jcol] = h1reg[half];
        out[base + 65536          + b*HH + jcol] = c0reg[half];
        out[base + 65536 + 32768  + b*HH + jcol] = c1reg[half];
    }
}

// ---------------- launch ----------------
extern "C" void kernel_launch(void* const* d_in, const int* in_sizes, int n_in,
                              void* d_out, int out_size, void* d_ws, size_t ws_size,
                              hipStream_t stream)
{
    const float* input = (const float*)d_in[0];
    const float* h0in  = (const float*)d_in[1];
    const float* c0in  = (const float*)d_in[2];
    const float* Wih0  = (const float*)d_in[3];
    const float* Whh0  = (const float*)d_in[4];
    const float* bih0  = (const float*)d_in[5];
    const float* bhh0  = (const float*)d_in[6];
    const float* Wih1  = (const float*)d_in[7];
    const float* Whh1  = (const float*)d_in[8];
    const float* bih1  = (const float*)d_in[9];
    const float* bhh1  = (const float*)d_in[10];
    const float* eyw1  = (const float*)d_in[11];
    const float* eyb1  = (const float*)d_in[12];
    const float* eyw2  = (const float*)d_in[13];
    const float* eyb2  = (const float*)d_in[14];
    const float* eyw3  = (const float*)d_in[15];
    const float* eyb3  = (const float*)d_in[16];
    const float* ehw1  = (const float*)d_in[17];
    const float* ehb1  = (const float*)d_in[18];
    const float* ehw2  = (const float*)d_in[19];
    const float* ehb2  = (const float*)d_in[20];
    const float* ehw3  = (const float*)d_in[21];
    const float* ehb3  = (const float*)d_in[22];

    float* out = (float*)d_out;
    float* ws  = (float*)d_ws;

    // ws layout (4B units)
    uint32_t* xprime = (uint32_t*)ws;                  // [T][B][I] packed
    uint32_t* hpack  = (uint32_t*)(ws + 33554432);     // h0,h1,ht0,ht1
    int*      bar    = (int*)(ws + 33685504);          // 8 arrival lines + release
    ushort*   wpack  = (ushort*)(ws + 33751104);       // 14,680,064 B
    ushort*   epack  = (ushort*)(ws + 37421120);       // 589,824 B

    hipFuncSetAttribute((const void*)persistent_kernel,
                        hipFuncAttributeMaxDynamicSharedMemorySize, 139264);

    init_state_kernel<<<256, 256, 0, stream>>>(h0in, hpack, bar);
    prep_pack_kernel<<<128*56, 64, 0, stream>>>(Wih0, Whh0, Wih1, Whh1, wpack);
    enc_pack_kernel<<<288, 64, 0, stream>>>(ehw1, ehw2, ehw3, epack);
    ency_kernel<<<4096, 256, 0, stream>>>(input, xprime,
                                          eyw1, eyb1, eyw2, eyb2, eyw3, eyb3);
    enc_only_kernel<<<16, 256, 0, stream>>>(hpack, hpack + 65536,
                                            ehw1, ehb1, ehw2, ehb2, ehw3, ehb3);
    persistent_kernel<<<NWG, 256, 139264, stream>>>(
        xprime, hpack, wpack, epack, c0in,
        bih0, bhh0, bih1, bhh1,
        ehb1, ehb2, ehb3,
        out, bar);
}